// Round 2
// baseline (5309.985 us; speedup 1.0000x reference)
//
#include <hip/hip_runtime.h>
#include <hip/hip_bf16.h>
#include <math.h>

// ---- problem constants ----
#define S_LEN   197
#define NPATCH  196
#define BATCHSZ 32
#define DMODEL  768
#define NHEAD   12
#define HDIM    64
#define FFDIM   3072
#define NLAYER  12
#define NCLS    1000
#define NTOK    (BATCHSZ * S_LEN)   // 6304

#define FLAG_BIAS    1
#define FLAG_RESID   2
#define FLAG_GELU    4
#define FLAG_OUTBF16 8

typedef __attribute__((ext_vector_type(8))) short short8;
typedef __attribute__((ext_vector_type(4))) float f32x4;
typedef __hip_bfloat16 bf16;

#define GLOBAL_AS __attribute__((address_space(1)))
#define LDS_AS    __attribute__((address_space(3)))

static __device__ __forceinline__ short bf16bits(float x) {
    bf16 b = __float2bfloat16(x);
    return *reinterpret_cast<short*>(&b);
}

// =====================================================================
// patch extraction -> bf16 patches [32*196, 768]
// =====================================================================
__global__ __launch_bounds__(256) void extract_patches_k(
    const float* __restrict__ images, bf16* __restrict__ patches)
{
    int r = blockIdx.x;              // b*196 + p
    int b = r / NPATCH, p = r - b * NPATCH;
    int i = p / 14, j = p - i * 14;
    int tid = threadIdx.x;
#pragma unroll
    for (int t = 0; t < 3; ++t) {
        int k = tid + t * 256;       // 0..767
        int pi = k / 48;
        int rem = k - pi * 48;
        int pj = rem / 3;
        int c  = rem - pj * 3;
        long long src = (((long long)(b * 224 + i * 16 + pi)) * 224 + (j * 16 + pj)) * 3 + c;
        patches[(long long)r * 768 + k] = __float2bfloat16(images[src]);
    }
}

// x[b,s,:] = s==0 ? cls : ptmp[b*196+s-1,:] + pos[s-1,:]
__global__ __launch_bounds__(256) void embed_k(
    const float* __restrict__ ptmp, const float* __restrict__ pos,
    const float* __restrict__ cls, float* __restrict__ x)
{
    long long idx = (long long)blockIdx.x * 256 + threadIdx.x;  // 32*197*768
    int d = idx % DMODEL;
    long long r = idx / DMODEL;
    int b = r / S_LEN, s = r - (long long)b * S_LEN;
    float v;
    if (s == 0) v = cls[d];
    else v = ptmp[((long long)b * NPATCH + s - 1) * DMODEL + d] + pos[(long long)(s - 1) * DMODEL + d];
    x[idx] = v;
}

// =====================================================================
// tiled transpose + convert (patch_W only)
// =====================================================================
__global__ __launch_bounds__(256) void transpose_conv_k(
    const float* __restrict__ src, bf16* __restrict__ dst, int R, int C)
{
    __shared__ float t[32][33];
    int tx = threadIdx.x & 31, ty = threadIdx.x >> 5;
    int c0 = blockIdx.x * 32, r0 = blockIdx.y * 32;
#pragma unroll
    for (int i = 0; i < 4; ++i) {
        int r = r0 + ty + i * 8;
        if (r < R && c0 + tx < C) t[ty + i * 8][tx] = src[(long long)r * C + c0 + tx];
    }
    __syncthreads();
#pragma unroll
    for (int i = 0; i < 4; ++i) {
        int c = c0 + ty + i * 8;
        if (c < C && r0 + tx < R) dst[(long long)c * R + r0 + tx] = __float2bfloat16(t[tx][ty + i * 8]);
    }
}

// =====================================================================
// per-layer weight conversion -> bf16 [N][K] + qkv bias pack
// =====================================================================
__global__ __launch_bounds__(256) void conv_layer_k(
    const float* __restrict__ Wq, const float* __restrict__ Wk, const float* __restrict__ Wv,
    const float* __restrict__ Wo, const float* __restrict__ W1, const float* __restrict__ W2,
    const float* __restrict__ bq, const float* __restrict__ bk, const float* __restrict__ bv,
    bf16* __restrict__ wqkv_t, bf16* __restrict__ wo_t,
    bf16* __restrict__ w1_t, bf16* __restrict__ w2_t, float* __restrict__ bqkv)
{
    int t = blockIdx.x;
    int tid = threadIdx.x;
    if (t == 6912) {
        for (int i = tid; i < 2304; i += 256) {
            int m = i / 768, r = i - m * 768;
            bqkv[i] = (m == 0 ? bq : m == 1 ? bk : bv)[r];
        }
        return;
    }
    const float* src; bf16* dst;
    int C; long long dld;
    int r0, c0;
    if (t < 1728) {
        int slab = t / 48, rem = t - slab * 48;
        int mat = slab / 12, h = slab - mat * 12;
        src = (mat == 0 ? Wq : mat == 1 ? Wk : Wv) + (long long)h * 768 * 64;
        dst = wqkv_t + ((long long)mat * 768 + h * 64) * 768;
        C = 64; dld = 768;
        r0 = (rem >> 1) * 32; c0 = (rem & 1) * 32;
    } else if (t < 2304) {
        int rem = t - 1728;
        src = Wo; dst = wo_t; C = 768; dld = 768;
        r0 = (rem / 24) * 32; c0 = (rem % 24) * 32;
    } else if (t < 4608) {
        int rem = t - 2304;
        src = W1; dst = w1_t; C = 3072; dld = 768;
        r0 = (rem / 96) * 32; c0 = (rem % 96) * 32;
    } else {
        int rem = t - 4608;
        src = W2; dst = w2_t; C = 768; dld = 3072;
        r0 = (rem / 24) * 32; c0 = (rem % 24) * 32;
    }
    __shared__ float tile[32][33];
    int tx = tid & 31, ty = tid >> 5;
#pragma unroll
    for (int i = 0; i < 4; ++i)
        tile[ty + i * 8][tx] = src[(long long)(r0 + ty + i * 8) * C + c0 + tx];
    __syncthreads();
#pragma unroll
    for (int i = 0; i < 4; ++i)
        dst[(long long)(c0 + ty + i * 8) * dld + r0 + tx] = __float2bfloat16(tile[tx][ty + i * 8]);
}

// =====================================================================
// V transpose: qkv bf16 -> Vt [384][64][224], zero pad s>=197
// =====================================================================
__global__ __launch_bounds__(256) void vt_k(
    const bf16* __restrict__ qkv, bf16* __restrict__ Vt)
{
    int z = blockIdx.z;
    int b = z / NHEAD, h = z - b * NHEAD;
    int s0 = blockIdx.x * 32, e0 = blockIdx.y * 32;
    __shared__ bf16 t[32][33];
    int tx = threadIdx.x & 31, ty = threadIdx.x >> 5;
#pragma unroll
    for (int i = 0; i < 4; ++i) {
        int s = s0 + ty + i * 8;
        bf16 v = __float2bfloat16(0.f);
        if (s < S_LEN) v = qkv[((long long)(b * S_LEN + s)) * 2304 + 1536 + h * 64 + e0 + tx];
        t[ty + i * 8][tx] = v;
    }
    __syncthreads();
#pragma unroll
    for (int i = 0; i < 4; ++i) {
        int e = e0 + ty + i * 8;
        Vt[((long long)z * 64 + e) * 224 + s0 + tx] = t[tx][ty + i * 8];
    }
}

// =====================================================================
// LayerNorm over last dim (768)
// =====================================================================
__global__ __launch_bounds__(256) void ln_k(
    const float* __restrict__ xin, long long instride,
    const float* __restrict__ g, const float* __restrict__ b,
    float* __restrict__ xout, long long outstride)
{
    int row = blockIdx.x;
    const float* xr = xin + (long long)row * instride;
    float* orow = xout + (long long)row * outstride;
    int tid = threadIdx.x;
    float v0 = xr[tid], v1 = xr[tid + 256], v2 = xr[tid + 512];
    __shared__ float s[256];
    s[tid] = v0 + v1 + v2;
    __syncthreads();
    for (int st = 128; st > 0; st >>= 1) { if (tid < st) s[tid] += s[tid + st]; __syncthreads(); }
    float mean = s[0] * (1.0f / DMODEL);
    __syncthreads();
    float d0 = v0 - mean, d1 = v1 - mean, d2 = v2 - mean;
    s[tid] = d0 * d0 + d1 * d1 + d2 * d2;
    __syncthreads();
    for (int st = 128; st > 0; st >>= 1) { if (tid < st) s[tid] += s[tid + st]; __syncthreads(); }
    float rs = rsqrtf(s[0] * (1.0f / DMODEL) + 1e-5f);
    orow[tid]       = d0 * rs * g[tid]       + b[tid];
    orow[tid + 256] = d1 * rs * g[tid + 256] + b[tid + 256];
    orow[tid + 512] = d2 * rs * g[tid + 512] + b[tid + 512];
}

__global__ __launch_bounds__(256) void ln_bf_k(
    const float* __restrict__ xin, long long instride,
    const float* __restrict__ g, const float* __restrict__ b,
    bf16* __restrict__ xout, long long outstride)
{
    int row = blockIdx.x;
    const float* xr = xin + (long long)row * instride;
    bf16* orow = xout + (long long)row * outstride;
    int tid = threadIdx.x;
    float v0 = xr[tid], v1 = xr[tid + 256], v2 = xr[tid + 512];
    __shared__ float s[256];
    s[tid] = v0 + v1 + v2;
    __syncthreads();
    for (int st = 128; st > 0; st >>= 1) { if (tid < st) s[tid] += s[tid + st]; __syncthreads(); }
    float mean = s[0] * (1.0f / DMODEL);
    __syncthreads();
    float d0 = v0 - mean, d1 = v1 - mean, d2 = v2 - mean;
    s[tid] = d0 * d0 + d1 * d1 + d2 * d2;
    __syncthreads();
    for (int st = 128; st > 0; st >>= 1) { if (tid < st) s[tid] += s[tid + st]; __syncthreads(); }
    float rs = rsqrtf(s[0] * (1.0f / DMODEL) + 1e-5f);
    orow[tid]       = __float2bfloat16(d0 * rs * g[tid]       + b[tid]);
    orow[tid + 256] = __float2bfloat16(d1 * rs * g[tid + 256] + b[tid + 256]);
    orow[tid + 512] = __float2bfloat16(d2 * rs * g[tid + 512] + b[tid + 512]);
}

// =====================================================================
// MFMA fused attention (unchanged — verified correct)
// =====================================================================
__global__ __launch_bounds__(256) void attn_k(
    const bf16* __restrict__ qkvb, const bf16* __restrict__ Vtb,
    bf16* __restrict__ Ob)
{
    __shared__ short KP[14336];
    __shared__ short Vs[14336];

    int tid = threadIdx.x;
    int lane = tid & 63, wid = tid >> 6;
    int rl = lane & 15, quad = lane >> 4;
    int qb = blockIdx.x;
    int z = blockIdx.y;
    int b = z / NHEAD, h = z - b * NHEAD;
    const short* qg = (const short*)qkvb;
    const short* vg = (const short*)Vtb;

#pragma unroll
    for (int c = 0; c < 7; ++c) {
        int f = wid * 7 + c;
        if (f < 26) {
            int jn = f >> 1, s = f & 1;
            int krow = jn * 16 + rl; if (krow > 196) krow = 196;
            const short* src = qg + ((long long)(b * S_LEN + krow) * 2304 + 768 + h * 64 + s * 32 + quad * 8);
            __builtin_amdgcn_global_load_lds((GLOBAL_AS const void*)src,
                                             (LDS_AS void*)&KP[f * 512], 16, 0, 0);
        }
        {
            int et = f / 7, s2 = f - et * 7;
            int e = et * 16 + rl;
            const short* src = vg + ((long long)(z * 64 + e) * 224 + s2 * 32 + quad * 8);
            __builtin_amdgcn_global_load_lds((GLOBAL_AS const void*)src,
                                             (LDS_AS void*)&Vs[f * 512], 16, 0, 0);
        }
    }
    int qrow = qb * 64 + wid * 16 + rl;
    int qrc = qrow > 196 ? 196 : qrow;
    long long qbase = (long long)(b * S_LEN + qrc) * 2304 + h * 64 + quad * 8;
    short8 q0 = *(const short8*)(qg + qbase);
    short8 q1 = *(const short8*)(qg + qbase + 32);
    __syncthreads();

    f32x4 accS[13];
#pragma unroll
    for (int jn = 0; jn < 13; ++jn) accS[jn] = (f32x4){0.f, 0.f, 0.f, 0.f};
#pragma unroll
    for (int jn = 0; jn < 13; ++jn) {
        short8 b0 = *(const short8*)&KP[(jn * 2 + 0) * 512 + lane * 8];
        short8 b1 = *(const short8*)&KP[(jn * 2 + 1) * 512 + lane * 8];
        accS[jn] = __builtin_amdgcn_mfma_f32_16x16x32_bf16(q0, b0, accS[jn], 0, 0, 0);
        accS[jn] = __builtin_amdgcn_mfma_f32_16x16x32_bf16(q1, b1, accS[jn], 0, 0, 0);
    }
    __syncthreads();

    float mx[4] = {-1e30f, -1e30f, -1e30f, -1e30f};
    float sm[4] = {0.f, 0.f, 0.f, 0.f};
#pragma unroll
    for (int r = 0; r < 4; ++r) {
#pragma unroll
        for (int jn = 0; jn < 13; ++jn) {
            int col = jn * 16 + rl;
            if (col < S_LEN) mx[r] = fmaxf(mx[r], accS[jn][r] * 0.125f);
        }
#pragma unroll
        for (int d = 1; d < 16; d <<= 1) mx[r] = fmaxf(mx[r], __shfl_xor(mx[r], d, 64));
    }
    float pv[13][4];
#pragma unroll
    for (int jn = 0; jn < 13; ++jn) {
        int col = jn * 16 + rl;
#pragma unroll
        for (int r = 0; r < 4; ++r) {
            float p = (col < S_LEN) ? __expf(accS[jn][r] * 0.125f - mx[r]) : 0.f;
            pv[jn][r] = p;
            sm[r] += p;
        }
    }
#pragma unroll
    for (int r = 0; r < 4; ++r) {
#pragma unroll
        for (int d = 1; d < 16; d <<= 1) sm[r] += __shfl_xor(sm[r], d, 64);
        sm[r] = 1.0f / sm[r];
    }

    int pbase = wid * 7 * 512;
#pragma unroll
    for (int jn = 0; jn < 13; ++jn) {
        int col = jn * 16 + rl;
        int s2 = col >> 5, kk = col & 31;
        int lidx = (kk >> 3) * 16, j = kk & 7;
#pragma unroll
        for (int r = 0; r < 4; ++r) {
            int m = quad * 4 + r;
            KP[pbase + s2 * 512 + (m + lidx) * 8 + j] = bf16bits(pv[jn][r] * sm[r]);
        }
    }
    {
        int col = 208 + rl;
        int kk = col & 31;
        int lidx = (kk >> 3) * 16, j = kk & 7;
#pragma unroll
        for (int r = 0; r < 4; ++r) {
            int m = quad * 4 + r;
            KP[pbase + 6 * 512 + (m + lidx) * 8 + j] = 0;
        }
    }

    short8 pa[7];
#pragma unroll
    for (int s2 = 0; s2 < 7; ++s2) pa[s2] = *(const short8*)&KP[pbase + s2 * 512 + lane * 8];
    f32x4 accO[4];
#pragma unroll
    for (int et = 0; et < 4; ++et) accO[et] = (f32x4){0.f, 0.f, 0.f, 0.f};
#pragma unroll
    for (int et = 0; et < 4; ++et)
#pragma unroll
        for (int s2 = 0; s2 < 7; ++s2) {
            short8 bb = *(const short8*)&Vs[(et * 7 + s2) * 512 + lane * 8];
            accO[et] = __builtin_amdgcn_mfma_f32_16x16x32_bf16(pa[s2], bb, accO[et], 0, 0, 0);
        }

#pragma unroll
    for (int et = 0; et < 4; ++et) {
        int e = et * 16 + rl;
#pragma unroll
        for (int r = 0; r < 4; ++r) {
            int q = qb * 64 + wid * 16 + quad * 4 + r;
            if (q < S_LEN)
                Ob[((long long)(b * S_LEN + q)) * DMODEL + h * 64 + e] = __float2bfloat16(accO[et][r]);
        }
    }
}

// =====================================================================
// head: out[b][n] = dot(xcls[b], head_W[:,n]) + bias[n]
// =====================================================================
__global__ __launch_bounds__(256) void head_k(
    const float* __restrict__ xcls, const float* __restrict__ W,
    const float* __restrict__ bias, float* __restrict__ out)
{
    int nt = blockIdx.x, b = blockIdx.y;
    int tid = threadIdx.x;
    int nl = tid & 63, kq = tid >> 6;
    int n = nt * 64 + nl;
    __shared__ float xs[DMODEL];
    for (int i = tid; i < DMODEL; i += 256) xs[i] = xcls[(long long)b * DMODEL + i];
    __syncthreads();
    float sum = 0.f;
    if (n < NCLS) {
        const float* Wp = W + (long long)kq * 192 * NCLS + n;
#pragma unroll 8
        for (int k = 0; k < 192; ++k)
            sum = fmaf(xs[kq * 192 + k], Wp[(long long)k * NCLS], sum);
    }
    __shared__ float red[256];
    red[tid] = sum;
    __syncthreads();
    if (kq == 0 && n < NCLS)
        out[(long long)b * NCLS + n] = red[nl] + red[nl + 64] + red[nl + 128] + red[nl + 192] + bias[n];
}

// x[i] += t0[i] + t1[i] + b2[col]   (float4 vectorized, 768 cols)
__global__ __launch_bounds__(256) void resid2_k(
    const float* __restrict__ t0, const float* __restrict__ t1,
    const float* __restrict__ b2, float* __restrict__ x)
{
    long long i = (long long)blockIdx.x * 256 + threadIdx.x;   // float4 index
    int col4 = i % (DMODEL / 4);
    const f32x4* t0v = (const f32x4*)t0;
    const f32x4* t1v = (const f32x4*)t1;
    const f32x4* b2v = (const f32x4*)b2;
    f32x4* xv = (f32x4*)x;
    f32x4 v = xv[i];
    f32x4 a = t0v[i], b = t1v[i], c = b2v[col4];
    v.x += a.x + b.x + c.x;
    v.y += a.y + b.y + c.y;
    v.z += a.z + b.z + c.z;
    v.w += a.w + b.w + c.w;
    xv[i] = v;
}

// =====================================================================
// bf16 MFMA GEMM, 128x128 tile, BK=64 (2 k-halves per barrier),
// hoisted incremental staging pointers, fast GELU epilogue.
// A [M][lda], Bt [N][ldb] both bf16. Requires K%64==0, N%128==0.
// =====================================================================
__global__ __launch_bounds__(256) void mfma_gemm_k(
    const bf16* __restrict__ A, const bf16* __restrict__ Bt,
    const float* __restrict__ bias, const float* __restrict__ resid,
    float* __restrict__ Cf, bf16* __restrict__ Cb,
    int M, int N, int K, int lda, int ldb, int ldc, int ldr,
    long long zA, long long zB, long long zC, int flags)
{
    __shared__ short As[8192];   // 8 M-frags x 2 kh x 512 shorts = 16KB
    __shared__ short Bs[8192];   // 8 N-frags x 2 kh x 512 shorts = 16KB

    int tid = threadIdx.x;
    int lane = tid & 63, wid = tid >> 6;
    int wm = wid & 1, wn = wid >> 1;
    long long block_m = (long long)blockIdx.y * 128;
    long long block_n = (long long)blockIdx.x * 128;
    int zz = blockIdx.z;

    const short* Ag = (const short*)A + zz * zA;
    const short* Bg = (const short*)Bt + zz * zB;
    if (Cf) Cf += zz * zC;
    if (Cb) Cb += zz * zC;

    int rl   = lane & 15;
    int quad = lane >> 4;

    // per-thread staging pointers: waves 0-1 stage A (16 blocks), waves 2-3 stage B.
    // block bi = f*2 + kh, each 512 shorts, lane-ordered (row = lane&15, kcol chunk = lane>>4).
    const short* src[8];
    short* dst[8];
#pragma unroll
    for (int c = 0; c < 8; ++c) {
        int bi = wid * 8 + c;
        if (bi < 16) {
            int f = bi >> 1, kh = bi & 1;
            long long grow = block_m + f * 16 + rl;
            if (grow >= M) grow = M - 1;
            src[c] = Ag + grow * lda + kh * 32 + quad * 8;
            dst[c] = &As[bi * 512];
        } else {
            int bj = bi - 16;
            int f = bj >> 1, kh = bj & 1;
            long long grow = block_n + f * 16 + rl;
            src[c] = Bg + grow * ldb + kh * 32 + quad * 8;
            dst[c] = &Bs[bj * 512];
        }
    }

    f32x4 acc[4][4] = {};

    for (int k0 = 0; k0 < K; k0 += 64) {
#pragma unroll
        for (int c = 0; c < 8; ++c) {
            __builtin_amdgcn_global_load_lds((GLOBAL_AS const void*)src[c],
                                             (LDS_AS void*)dst[c], 16, 0, 0);
            src[c] += 64;
        }
        __syncthreads();

        const short8* ap = (const short8*)As;
        const short8* bp = (const short8*)Bs;
#pragma unroll
        for (int kh = 0; kh < 2; ++kh) {
            short8 a[4], b[4];
#pragma unroll
            for (int i = 0; i < 4; ++i) a[i] = ap[((wm * 4 + i) * 2 + kh) * 64 + lane];
#pragma unroll
            for (int j = 0; j < 4; ++j) b[j] = bp[((wn * 4 + j) * 2 + kh) * 64 + lane];
#pragma unroll
            for (int i = 0; i < 4; ++i)
#pragma unroll
                for (int j = 0; j < 4; ++j)
                    acc[i][j] = __builtin_amdgcn_mfma_f32_16x16x32_bf16(a[i], b[j], acc[i][j], 0, 0, 0);
        }
        __syncthreads();
    }

    int cl = lane & 15;
    int rq = (lane >> 4) * 4;
#pragma unroll
    for (int j = 0; j < 4; ++j) {
        long long col = block_n + wn * 64 + j * 16 + cl;
        float bv = (flags & FLAG_BIAS) ? bias[col] : 0.f;
#pragma unroll
        for (int i = 0; i < 4; ++i) {
#pragma unroll
            for (int r = 0; r < 4; ++r) {
                long long row = block_m + wm * 64 + i * 16 + rq + r;
                if (row >= M) continue;
                float v = acc[i][j][r] + bv;
                if (flags & FLAG_GELU) {
                    // tanh-form GELU as sigmoid: v * sigma(1.5957691*(v + 0.044715 v^3))
                    // max |diff| vs exact erf-GELU ~1e-3 in h1, below bf16 rounding of h1.
                    float z = 1.5957691216f * v * (1.0f + 0.044715f * v * v);
                    v = v / (1.0f + __expf(-z));
                }
                if (flags & FLAG_RESID) v += resid[row * (long long)ldr + col];
                if (flags & FLAG_OUTBF16) Cb[row * (long long)ldc + col] = __float2bfloat16(v);
                else Cf[row * (long long)ldc + col] = v;
            }
        }
    }
}

static inline void launch_mfma(hipStream_t stream,
    const bf16* A, const bf16* Bt, const float* bias, const float* resid,
    float* Cf, bf16* Cb, int M, int N, int K, int ldc, int ldr, int flags)
{
    dim3 grid(N / 128, (M + 127) / 128, 1);
    mfma_gemm_k<<<grid, dim3(256), 0, stream>>>(A, Bt, bias, resid, Cf, Cb,
        M, N, K, K, K, ldc, ldr, 0, 0, 0, flags);
}

extern "C" void kernel_launch(void* const* d_in, const int* in_sizes, int n_in,
                              void* d_out, int out_size, void* d_ws, size_t ws_size,
                              hipStream_t stream)
{
    const float* images   = (const float*)d_in[0];
    const float* patch_W  = (const float*)d_in[1];
    const float* patch_b  = (const float*)d_in[2];
    const float* pos_emb  = (const float*)d_in[3];
    const float* cls      = (const float*)d_in[4];
    const float* ln1_g    = (const float*)d_in[5];
    const float* ln1_b    = (const float*)d_in[6];
    const float* Wq       = (const float*)d_in[7];
    const float* bq       = (const float*)d_in[8];
    const float* Wk       = (const float*)d_in[9];
    const float* bk       = (const float*)d_in[10];
    const float* Wv       = (const float*)d_in[11];
    const float* bv       = (const float*)d_in[12];
    const float* Wo       = (const float*)d_in[13];
    const float* bo       = (const float*)d_in[14];
    const float* ln2_g    = (const float*)d_in[15];
    const float* ln2_b    = (const float*)d_in[16];
    const float* W1       = (const float*)d_in[17];
    const float* b1       = (const float*)d_in[18];
    const float* W2       = (const float*)d_in[19];
    const float* b2       = (const float*)d_in[20];
    const float* head_g   = (const float*)d_in[21];
    const float* head_bn  = (const float*)d_in[22];
    const float* head_W   = (const float*)d_in[23];
    const float* head_bias= (const float*)d_in[24];
    float* out = (float*)d_out;

    // ---- workspace carve-up ----
    char* p = (char*)d_ws;
    auto alloc = [&](long long nbytes) { char* r = p; p += (nbytes + 255) & ~255LL; return r; };
    const long long SZ = (long long)NTOK * DMODEL;

    float* x      = (float*)alloc(SZ * 4);                          // residual fp32
    bf16*  xn     = (bf16*) alloc(SZ * 2);                          // LN out bf16
    bf16*  qkvb   = (bf16*) alloc((long long)NTOK * 2304 * 2);      // qkv bf16 (union ptmp fp32)
    float* ptmp   = (float*)qkvb;                                   // [6272,768] fp32
    bf16*  Vt     = (bf16*) alloc((long long)384 * 64 * 224 * 2);   // V transposed, padded
    bf16*  h1     = (bf16*) alloc((long long)NTOK * FFDIM * 2);     // FFN mid
    float* w2tmp  = (float*)alloc(2 * SZ * 4);                      // split-K partials
    bf16*  Ob     = (bf16*) alloc(SZ * 2);                          // attn out (union patches)
    bf16*  patches= Ob;
    bf16*  wqkv_t = (bf16*) alloc((long long)2304 * 768 * 2);
    bf16*  wo_t   = (bf16*) alloc((long long)768 * 768 * 2);
    bf16*  w1_t   = (bf16*) alloc((long long)3072 * 768 * 2);
    bf16*  w2_t   = (bf16*) alloc((long long)768 * 3072 * 2);
    bf16*  pw_t   = (bf16*) alloc((long long)768 * 768 * 2);
    float* bqkv   = (float*)alloc(2304 * 4);
    float* xcls   = (float*)alloc((long long)BATCHSZ * DMODEL * 4);

    // ---- embed ----
    extract_patches_k<<<dim3(BATCHSZ * NPATCH), dim3(256), 0, stream>>>(images, patches);
    transpose_conv_k<<<dim3(24, 24), dim3(256), 0, stream>>>(patch_W, pw_t, 768, 768);
    launch_mfma(stream, patches, pw_t, patch_b, nullptr, ptmp, nullptr,
                BATCHSZ * NPATCH, DMODEL, 768, DMODEL, 0, FLAG_BIAS);
    embed_k<<<dim3((int)(SZ / 256)), dim3(256), 0, stream>>>(ptmp, pos_emb, cls, x);

    const long long WQKV_L = (long long)NHEAD * DMODEL * HDIM;
    for (int l = 0; l < NLAYER; ++l) {
        conv_layer_k<<<dim3(6913), dim3(256), 0, stream>>>(
            Wq + (long long)l * WQKV_L, Wk + (long long)l * WQKV_L, Wv + (long long)l * WQKV_L,
            Wo + (long long)l * DMODEL * DMODEL,
            W1 + (long long)l * DMODEL * FFDIM,
            W2 + (long long)l * FFDIM * DMODEL,
            bq + (long long)l * 768, bk + (long long)l * 768, bv + (long long)l * 768,
            wqkv_t, wo_t, w1_t, w2_t, bqkv);

        // ln1 -> bf16
        ln_bf_k<<<dim3(NTOK), dim3(256), 0, stream>>>(
            x, DMODEL, ln1_g + l * DMODEL, ln1_b + l * DMODEL, xn, DMODEL);

        // fused QKV -> bf16 [6304][2304]
        launch_mfma(stream, xn, wqkv_t, bqkv, nullptr, nullptr, qkvb,
                    NTOK, 2304, DMODEL, 2304, 0, FLAG_BIAS | FLAG_OUTBF16);

        // V transpose
        vt_k<<<dim3(7, 2, 384), dim3(256), 0, stream>>>(qkvb, Vt);

        // fused MFMA attention -> Ob
        attn_k<<<dim3(4, 384), dim3(256), 0, stream>>>(qkvb, Vt, Ob);

        // x += Ob @ Wo + bo
        launch_mfma(stream, Ob, wo_t, bo + (long long)l * DMODEL, x, x, nullptr,
                    NTOK, DMODEL, DMODEL, DMODEL, DMODEL, FLAG_BIAS | FLAG_RESID);

        // ln2 -> bf16
        ln_bf_k<<<dim3(NTOK), dim3(256), 0, stream>>>(
            x, DMODEL, ln2_g + l * DMODEL, ln2_b + l * DMODEL, xn, DMODEL);

        // h1 = gelu(xn @ W1 + b1)
        launch_mfma(stream, xn, w1_t, b1 + (long long)l * FFDIM, nullptr, nullptr, h1,
                    NTOK, FFDIM, DMODEL, FFDIM, 0, FLAG_BIAS | FLAG_GELU | FLAG_OUTBF16);

        // W2 GEMM split-K (z=2, K=1536 each) -> w2tmp, then x += t0+t1+b2
        {
            dim3 grid(DMODEL / 128, (NTOK + 127) / 128, 2);
            mfma_gemm_k<<<grid, dim3(256), 0, stream>>>(
                h1, w2_t, nullptr, nullptr, w2tmp, nullptr,
                NTOK, DMODEL, 1536, FFDIM, FFDIM, DMODEL, 0,
                1536, 1536, SZ, 0);
            resid2_k<<<dim3((int)(SZ / 4 / 256)), dim3(256), 0, stream>>>(
                w2tmp, w2tmp + SZ, b2 + (long long)l * DMODEL, x);
        }
    }

    // ---- head ----
    ln_k<<<dim3(BATCHSZ), dim3(256), 0, stream>>>(
        x, (long long)S_LEN * DMODEL, head_g, head_bn, xcls, DMODEL);
    head_k<<<dim3(16, BATCHSZ), dim3(256), 0, stream>>>(xcls, head_W, head_bias, out);
}

// Round 3
// 4431.958 us; speedup vs baseline: 1.1981x; 1.1981x over previous
//
#include <hip/hip_runtime.h>
#include <hip/hip_bf16.h>
#include <math.h>

// ---- problem constants ----
#define S_LEN   197
#define NPATCH  196
#define BATCHSZ 32
#define DMODEL  768
#define NHEAD   12
#define HDIM    64
#define FFDIM   3072
#define NLAYER  12
#define NCLS    1000
#define NTOK    (BATCHSZ * S_LEN)   // 6304

#define FLAG_BIAS    1
#define FLAG_RESID   2
#define FLAG_GELU    4
#define FLAG_OUTBF16 8

typedef __attribute__((ext_vector_type(8))) short short8;
typedef __attribute__((ext_vector_type(4))) float f32x4;
typedef __hip_bfloat16 bf16;

#define GLOBAL_AS __attribute__((address_space(1)))
#define LDS_AS    __attribute__((address_space(3)))

static __device__ __forceinline__ short bf16bits(float x) {
    bf16 b = __float2bfloat16(x);
    return *reinterpret_cast<short*>(&b);
}

// =====================================================================
// patch extraction -> bf16 patches [32*196, 768]
// =====================================================================
__global__ __launch_bounds__(256) void extract_patches_k(
    const float* __restrict__ images, bf16* __restrict__ patches)
{
    int r = blockIdx.x;              // b*196 + p
    int b = r / NPATCH, p = r - b * NPATCH;
    int i = p / 14, j = p - i * 14;
    int tid = threadIdx.x;
#pragma unroll
    for (int t = 0; t < 3; ++t) {
        int k = tid + t * 256;       // 0..767
        int pi = k / 48;
        int rem = k - pi * 48;
        int pj = rem / 3;
        int c  = rem - pj * 3;
        long long src = (((long long)(b * 224 + i * 16 + pi)) * 224 + (j * 16 + pj)) * 3 + c;
        patches[(long long)r * 768 + k] = __float2bfloat16(images[src]);
    }
}

// x[b,s,:] = s==0 ? cls : ptmp[b*196+s-1,:] + pos[s-1,:]
__global__ __launch_bounds__(256) void embed_k(
    const float* __restrict__ ptmp, const float* __restrict__ pos,
    const float* __restrict__ cls, float* __restrict__ x)
{
    long long idx = (long long)blockIdx.x * 256 + threadIdx.x;  // 32*197*768
    int d = idx % DMODEL;
    long long r = idx / DMODEL;
    int b = r / S_LEN, s = r - (long long)b * S_LEN;
    float v;
    if (s == 0) v = cls[d];
    else v = ptmp[((long long)b * NPATCH + s - 1) * DMODEL + d] + pos[(long long)(s - 1) * DMODEL + d];
    x[idx] = v;
}

// =====================================================================
// tiled transpose + convert (patch_W only)
// =====================================================================
__global__ __launch_bounds__(256) void transpose_conv_k(
    const float* __restrict__ src, bf16* __restrict__ dst, int R, int C)
{
    __shared__ float t[32][33];
    int tx = threadIdx.x & 31, ty = threadIdx.x >> 5;
    int c0 = blockIdx.x * 32, r0 = blockIdx.y * 32;
#pragma unroll
    for (int i = 0; i < 4; ++i) {
        int r = r0 + ty + i * 8;
        if (r < R && c0 + tx < C) t[ty + i * 8][tx] = src[(long long)r * C + c0 + tx];
    }
    __syncthreads();
#pragma unroll
    for (int i = 0; i < 4; ++i) {
        int c = c0 + ty + i * 8;
        if (c < C && r0 + tx < R) dst[(long long)c * R + r0 + tx] = __float2bfloat16(t[tx][ty + i * 8]);
    }
}

// =====================================================================
// per-layer weight conversion -> bf16 [N][K] + qkv bias pack
// =====================================================================
__global__ __launch_bounds__(256) void conv_layer_k(
    const float* __restrict__ Wq, const float* __restrict__ Wk, const float* __restrict__ Wv,
    const float* __restrict__ Wo, const float* __restrict__ W1, const float* __restrict__ W2,
    const float* __restrict__ bq, const float* __restrict__ bk, const float* __restrict__ bv,
    bf16* __restrict__ wqkv_t, bf16* __restrict__ wo_t,
    bf16* __restrict__ w1_t, bf16* __restrict__ w2_t, float* __restrict__ bqkv)
{
    int t = blockIdx.x;
    int tid = threadIdx.x;
    if (t == 6912) {
        for (int i = tid; i < 2304; i += 256) {
            int m = i / 768, r = i - m * 768;
            bqkv[i] = (m == 0 ? bq : m == 1 ? bk : bv)[r];
        }
        return;
    }
    const float* src; bf16* dst;
    int C; long long dld;
    int r0, c0;
    if (t < 1728) {
        int slab = t / 48, rem = t - slab * 48;
        int mat = slab / 12, h = slab - mat * 12;
        src = (mat == 0 ? Wq : mat == 1 ? Wk : Wv) + (long long)h * 768 * 64;
        dst = wqkv_t + ((long long)mat * 768 + h * 64) * 768;
        C = 64; dld = 768;
        r0 = (rem >> 1) * 32; c0 = (rem & 1) * 32;
    } else if (t < 2304) {
        int rem = t - 1728;
        src = Wo; dst = wo_t; C = 768; dld = 768;
        r0 = (rem / 24) * 32; c0 = (rem % 24) * 32;
    } else if (t < 4608) {
        int rem = t - 2304;
        src = W1; dst = w1_t; C = 3072; dld = 768;
        r0 = (rem / 96) * 32; c0 = (rem % 96) * 32;
    } else {
        int rem = t - 4608;
        src = W2; dst = w2_t; C = 768; dld = 3072;
        r0 = (rem / 24) * 32; c0 = (rem % 24) * 32;
    }
    __shared__ float tile[32][33];
    int tx = tid & 31, ty = tid >> 5;
#pragma unroll
    for (int i = 0; i < 4; ++i)
        tile[ty + i * 8][tx] = src[(long long)(r0 + ty + i * 8) * C + c0 + tx];
    __syncthreads();
#pragma unroll
    for (int i = 0; i < 4; ++i)
        dst[(long long)(c0 + ty + i * 8) * dld + r0 + tx] = __float2bfloat16(tile[tx][ty + i * 8]);
}

// =====================================================================
// V transpose: qkv bf16 -> Vt [384][64][224], zero pad s>=197
// =====================================================================
__global__ __launch_bounds__(256) void vt_k(
    const bf16* __restrict__ qkv, bf16* __restrict__ Vt)
{
    int z = blockIdx.z;
    int b = z / NHEAD, h = z - b * NHEAD;
    int s0 = blockIdx.x * 32, e0 = blockIdx.y * 32;
    __shared__ bf16 t[32][33];
    int tx = threadIdx.x & 31, ty = threadIdx.x >> 5;
#pragma unroll
    for (int i = 0; i < 4; ++i) {
        int s = s0 + ty + i * 8;
        bf16 v = __float2bfloat16(0.f);
        if (s < S_LEN) v = qkv[((long long)(b * S_LEN + s)) * 2304 + 1536 + h * 64 + e0 + tx];
        t[ty + i * 8][tx] = v;
    }
    __syncthreads();
#pragma unroll
    for (int i = 0; i < 4; ++i) {
        int e = e0 + ty + i * 8;
        Vt[((long long)z * 64 + e) * 224 + s0 + tx] = t[tx][ty + i * 8];
    }
}

// =====================================================================
// LayerNorm over last dim (768)
// =====================================================================
__global__ __launch_bounds__(256) void ln_k(
    const float* __restrict__ xin, long long instride,
    const float* __restrict__ g, const float* __restrict__ b,
    float* __restrict__ xout, long long outstride)
{
    int row = blockIdx.x;
    const float* xr = xin + (long long)row * instride;
    float* orow = xout + (long long)row * outstride;
    int tid = threadIdx.x;
    float v0 = xr[tid], v1 = xr[tid + 256], v2 = xr[tid + 512];
    __shared__ float s[256];
    s[tid] = v0 + v1 + v2;
    __syncthreads();
    for (int st = 128; st > 0; st >>= 1) { if (tid < st) s[tid] += s[tid + st]; __syncthreads(); }
    float mean = s[0] * (1.0f / DMODEL);
    __syncthreads();
    float d0 = v0 - mean, d1 = v1 - mean, d2 = v2 - mean;
    s[tid] = d0 * d0 + d1 * d1 + d2 * d2;
    __syncthreads();
    for (int st = 128; st > 0; st >>= 1) { if (tid < st) s[tid] += s[tid + st]; __syncthreads(); }
    float rs = rsqrtf(s[0] * (1.0f / DMODEL) + 1e-5f);
    orow[tid]       = d0 * rs * g[tid]       + b[tid];
    orow[tid + 256] = d1 * rs * g[tid + 256] + b[tid + 256];
    orow[tid + 512] = d2 * rs * g[tid + 512] + b[tid + 512];
}

__global__ __launch_bounds__(256) void ln_bf_k(
    const float* __restrict__ xin, long long instride,
    const float* __restrict__ g, const float* __restrict__ b,
    bf16* __restrict__ xout, long long outstride)
{
    int row = blockIdx.x;
    const float* xr = xin + (long long)row * instride;
    bf16* orow = xout + (long long)row * outstride;
    int tid = threadIdx.x;
    float v0 = xr[tid], v1 = xr[tid + 256], v2 = xr[tid + 512];
    __shared__ float s[256];
    s[tid] = v0 + v1 + v2;
    __syncthreads();
    for (int st = 128; st > 0; st >>= 1) { if (tid < st) s[tid] += s[tid + st]; __syncthreads(); }
    float mean = s[0] * (1.0f / DMODEL);
    __syncthreads();
    float d0 = v0 - mean, d1 = v1 - mean, d2 = v2 - mean;
    s[tid] = d0 * d0 + d1 * d1 + d2 * d2;
    __syncthreads();
    for (int st = 128; st > 0; st >>= 1) { if (tid < st) s[tid] += s[tid + st]; __syncthreads(); }
    float rs = rsqrtf(s[0] * (1.0f / DMODEL) + 1e-5f);
    orow[tid]       = __float2bfloat16(d0 * rs * g[tid]       + b[tid]);
    orow[tid + 256] = __float2bfloat16(d1 * rs * g[tid + 256] + b[tid + 256]);
    orow[tid + 512] = __float2bfloat16(d2 * rs * g[tid + 512] + b[tid + 512]);
}

// =====================================================================
// MFMA fused attention (unchanged — verified correct)
// =====================================================================
__global__ __launch_bounds__(256) void attn_k(
    const bf16* __restrict__ qkvb, const bf16* __restrict__ Vtb,
    bf16* __restrict__ Ob)
{
    __shared__ short KP[14336];
    __shared__ short Vs[14336];

    int tid = threadIdx.x;
    int lane = tid & 63, wid = tid >> 6;
    int rl = lane & 15, quad = lane >> 4;
    int qb = blockIdx.x;
    int z = blockIdx.y;
    int b = z / NHEAD, h = z - b * NHEAD;
    const short* qg = (const short*)qkvb;
    const short* vg = (const short*)Vtb;

#pragma unroll
    for (int c = 0; c < 7; ++c) {
        int f = wid * 7 + c;
        if (f < 26) {
            int jn = f >> 1, s = f & 1;
            int krow = jn * 16 + rl; if (krow > 196) krow = 196;
            const short* src = qg + ((long long)(b * S_LEN + krow) * 2304 + 768 + h * 64 + s * 32 + quad * 8);
            __builtin_amdgcn_global_load_lds((GLOBAL_AS const void*)src,
                                             (LDS_AS void*)&KP[f * 512], 16, 0, 0);
        }
        {
            int et = f / 7, s2 = f - et * 7;
            int e = et * 16 + rl;
            const short* src = vg + ((long long)(z * 64 + e) * 224 + s2 * 32 + quad * 8);
            __builtin_amdgcn_global_load_lds((GLOBAL_AS const void*)src,
                                             (LDS_AS void*)&Vs[f * 512], 16, 0, 0);
        }
    }
    int qrow = qb * 64 + wid * 16 + rl;
    int qrc = qrow > 196 ? 196 : qrow;
    long long qbase = (long long)(b * S_LEN + qrc) * 2304 + h * 64 + quad * 8;
    short8 q0 = *(const short8*)(qg + qbase);
    short8 q1 = *(const short8*)(qg + qbase + 32);
    __syncthreads();

    f32x4 accS[13];
#pragma unroll
    for (int jn = 0; jn < 13; ++jn) accS[jn] = (f32x4){0.f, 0.f, 0.f, 0.f};
#pragma unroll
    for (int jn = 0; jn < 13; ++jn) {
        short8 b0 = *(const short8*)&KP[(jn * 2 + 0) * 512 + lane * 8];
        short8 b1 = *(const short8*)&KP[(jn * 2 + 1) * 512 + lane * 8];
        accS[jn] = __builtin_amdgcn_mfma_f32_16x16x32_bf16(q0, b0, accS[jn], 0, 0, 0);
        accS[jn] = __builtin_amdgcn_mfma_f32_16x16x32_bf16(q1, b1, accS[jn], 0, 0, 0);
    }
    __syncthreads();

    float mx[4] = {-1e30f, -1e30f, -1e30f, -1e30f};
    float sm[4] = {0.f, 0.f, 0.f, 0.f};
#pragma unroll
    for (int r = 0; r < 4; ++r) {
#pragma unroll
        for (int jn = 0; jn < 13; ++jn) {
            int col = jn * 16 + rl;
            if (col < S_LEN) mx[r] = fmaxf(mx[r], accS[jn][r] * 0.125f);
        }
#pragma unroll
        for (int d = 1; d < 16; d <<= 1) mx[r] = fmaxf(mx[r], __shfl_xor(mx[r], d, 64));
    }
    float pv[13][4];
#pragma unroll
    for (int jn = 0; jn < 13; ++jn) {
        int col = jn * 16 + rl;
#pragma unroll
        for (int r = 0; r < 4; ++r) {
            float p = (col < S_LEN) ? __expf(accS[jn][r] * 0.125f - mx[r]) : 0.f;
            pv[jn][r] = p;
            sm[r] += p;
        }
    }
#pragma unroll
    for (int r = 0; r < 4; ++r) {
#pragma unroll
        for (int d = 1; d < 16; d <<= 1) sm[r] += __shfl_xor(sm[r], d, 64);
        sm[r] = 1.0f / sm[r];
    }

    int pbase = wid * 7 * 512;
#pragma unroll
    for (int jn = 0; jn < 13; ++jn) {
        int col = jn * 16 + rl;
        int s2 = col >> 5, kk = col & 31;
        int lidx = (kk >> 3) * 16, j = kk & 7;
#pragma unroll
        for (int r = 0; r < 4; ++r) {
            int m = quad * 4 + r;
            KP[pbase + s2 * 512 + (m + lidx) * 8 + j] = bf16bits(pv[jn][r] * sm[r]);
        }
    }
    {
        int col = 208 + rl;
        int kk = col & 31;
        int lidx = (kk >> 3) * 16, j = kk & 7;
#pragma unroll
        for (int r = 0; r < 4; ++r) {
            int m = quad * 4 + r;
            KP[pbase + 6 * 512 + (m + lidx) * 8 + j] = 0;
        }
    }

    short8 pa[7];
#pragma unroll
    for (int s2 = 0; s2 < 7; ++s2) pa[s2] = *(const short8*)&KP[pbase + s2 * 512 + lane * 8];
    f32x4 accO[4];
#pragma unroll
    for (int et = 0; et < 4; ++et) accO[et] = (f32x4){0.f, 0.f, 0.f, 0.f};
#pragma unroll
    for (int et = 0; et < 4; ++et)
#pragma unroll
        for (int s2 = 0; s2 < 7; ++s2) {
            short8 bb = *(const short8*)&Vs[(et * 7 + s2) * 512 + lane * 8];
            accO[et] = __builtin_amdgcn_mfma_f32_16x16x32_bf16(pa[s2], bb, accO[et], 0, 0, 0);
        }

#pragma unroll
    for (int et = 0; et < 4; ++et) {
        int e = et * 16 + rl;
#pragma unroll
        for (int r = 0; r < 4; ++r) {
            int q = qb * 64 + wid * 16 + quad * 4 + r;
            if (q < S_LEN)
                Ob[((long long)(b * S_LEN + q)) * DMODEL + h * 64 + e] = __float2bfloat16(accO[et][r]);
        }
    }
}

// =====================================================================
// head: out[b][n] = dot(xcls[b], head_W[:,n]) + bias[n]
// =====================================================================
__global__ __launch_bounds__(256) void head_k(
    const float* __restrict__ xcls, const float* __restrict__ W,
    const float* __restrict__ bias, float* __restrict__ out)
{
    int nt = blockIdx.x, b = blockIdx.y;
    int tid = threadIdx.x;
    int nl = tid & 63, kq = tid >> 6;
    int n = nt * 64 + nl;
    __shared__ float xs[DMODEL];
    for (int i = tid; i < DMODEL; i += 256) xs[i] = xcls[(long long)b * DMODEL + i];
    __syncthreads();
    float sum = 0.f;
    if (n < NCLS) {
        const float* Wp = W + (long long)kq * 192 * NCLS + n;
#pragma unroll 8
        for (int k = 0; k < 192; ++k)
            sum = fmaf(xs[kq * 192 + k], Wp[(long long)k * NCLS], sum);
    }
    __shared__ float red[256];
    red[tid] = sum;
    __syncthreads();
    if (kq == 0 && n < NCLS)
        out[(long long)b * NCLS + n] = red[nl] + red[nl + 64] + red[nl + 128] + red[nl + 192] + bias[n];
}

// x[i] += t0[i] + t1[i] + b2[col]   (float4 vectorized, 768 cols)
__global__ __launch_bounds__(256) void resid2_k(
    const float* __restrict__ t0, const float* __restrict__ t1,
    const float* __restrict__ b2, float* __restrict__ x)
{
    long long i = (long long)blockIdx.x * 256 + threadIdx.x;   // float4 index
    int col4 = i % (DMODEL / 4);
    const f32x4* t0v = (const f32x4*)t0;
    const f32x4* t1v = (const f32x4*)t1;
    const f32x4* b2v = (const f32x4*)b2;
    f32x4* xv = (f32x4*)x;
    f32x4 v = xv[i];
    f32x4 a = t0v[i], b = t1v[i], c = b2v[col4];
    v.x += a.x + b.x + c.x;
    v.y += a.y + b.y + c.y;
    v.z += a.z + b.z + c.z;
    v.w += a.w + b.w + c.w;
    xv[i] = v;
}

// =====================================================================
// bf16 MFMA GEMM, 128x128 tile, BK=32, 3-buffer 2-deep pipeline with
// counted vmcnt (raw s_barrier), bijective XCD chunked swizzle
// (m-fastest decomposition), j-inner coalesced epilogue stores,
// fast GELU.  A [M][lda], Bt [N][ldb] bf16; K%32==0, N%128==0.
// =====================================================================
__global__ __launch_bounds__(256) void mfma_gemm_k(
    const bf16* __restrict__ A, const bf16* __restrict__ Bt,
    const float* __restrict__ bias, const float* __restrict__ resid,
    float* __restrict__ Cf, bf16* __restrict__ Cb,
    int M, int N, int K, int lda, int ldb, int ldc, int ldr,
    long long zA, long long zB, long long zC, int flags)
{
    __shared__ short As[3 * 4096];   // 3 buffers x 8 blocks x 512 shorts = 24KB
    __shared__ short Bs[3 * 4096];   // 24KB

    int tid = threadIdx.x;
    int lane = tid & 63, wid = tid >> 6;
    int wm = wid & 1, wn = wid >> 1;

    // ---- bijective chunked XCD swizzle (m204); m-fastest decomposition ----
    int gx = gridDim.x, gy = gridDim.y;
    int nwg = gx * gy * gridDim.z;
    int lin = blockIdx.x + gx * (blockIdx.y + gy * blockIdx.z);
    int q8 = nwg >> 3, r8 = nwg & 7;
    int xcd = lin & 7, idx = lin >> 3;
    int wg = (xcd < r8) ? (xcd * (q8 + 1) + idx)
                        : (r8 * (q8 + 1) + (xcd - r8) * q8 + idx);
    int by = wg % gy;            // m-tile varies fastest within an XCD chunk
    int t2 = wg / gy;
    int bx = t2 % gx;            // -> each XCD owns a contiguous n-tile slab
    int bz = t2 / gx;

    long long block_m = (long long)by * 128;
    long long block_n = (long long)bx * 128;

    const short* Ag = (const short*)A + (long long)bz * zA;
    const short* Bg = (const short*)Bt + (long long)bz * zB;
    if (Cf) Cf += (long long)bz * zC;
    if (Cb) Cb += (long long)bz * zC;

    int rl   = lane & 15;
    int quad = lane >> 4;

    // per-thread staging roles: waves 0-1 stage A (blocks 0..7), waves 2-3 B.
    const short* srcp[4];
    short* dstb[4];
#pragma unroll
    for (int c = 0; c < 4; ++c) {
        int bi = wid * 4 + c;
        int f = bi & 7;
        if (bi < 8) {
            long long grow = block_m + f * 16 + rl;
            if (grow >= M) grow = M - 1;
            srcp[c] = Ag + grow * lda + quad * 8;
            dstb[c] = &As[f * 512];
        } else {
            long long grow = block_n + f * 16 + rl;
            srcp[c] = Bg + grow * ldb + quad * 8;
            dstb[c] = &Bs[f * 512];
        }
    }

#define STAGE(BUF) do {                                                        \
    _Pragma("unroll")                                                          \
    for (int c = 0; c < 4; ++c) {                                              \
        __builtin_amdgcn_global_load_lds((GLOBAL_AS const void*)srcp[c],       \
            (LDS_AS void*)(dstb[c] + (BUF) * 4096), 16, 0, 0);                 \
        srcp[c] += 32;                                                         \
    } } while (0)

    f32x4 acc[4][4] = {};

    int nt = K >> 5;                 // K/32 tiles (>= 24 for all call sites)
    // prologue: tiles 0,1 into buffers 0,1
    STAGE(0);
    STAGE(1);
    int sbuf = 2, cbuf = 0;

    for (int t = 0; t < nt; ++t) {
        if (t + 2 < nt) {
            STAGE(sbuf);
            sbuf = (sbuf == 2) ? 0 : sbuf + 1;
            asm volatile("s_waitcnt vmcnt(8)" ::: "memory");   // tile t landed
        } else if (t + 1 < nt) {
            asm volatile("s_waitcnt vmcnt(4)" ::: "memory");
        } else {
            asm volatile("s_waitcnt vmcnt(0)" ::: "memory");
        }
        __builtin_amdgcn_s_barrier();   // all waves' tile-t DMA complete

        const short8* ap = (const short8*)(As + cbuf * 4096);
        const short8* bp = (const short8*)(Bs + cbuf * 4096);
        short8 a[4], b[4];
#pragma unroll
        for (int i = 0; i < 4; ++i) a[i] = ap[(wm * 4 + i) * 64 + lane];
#pragma unroll
        for (int j = 0; j < 4; ++j) b[j] = bp[(wn * 4 + j) * 64 + lane];
#pragma unroll
        for (int i = 0; i < 4; ++i)
#pragma unroll
            for (int j = 0; j < 4; ++j)
                acc[i][j] = __builtin_amdgcn_mfma_f32_16x16x32_bf16(a[i], b[j], acc[i][j], 0, 0, 0);

        __builtin_amdgcn_s_barrier();   // everyone done reading cbuf
        cbuf = (cbuf == 2) ? 0 : cbuf + 1;
    }
#undef STAGE

    // ---- epilogue: j-inner so each (i,r) emits 4 consecutive 32B chunks ----
    int cl = lane & 15;
    int rq = (lane >> 4) * 4;
    float bv[4];
#pragma unroll
    for (int j = 0; j < 4; ++j)
        bv[j] = (flags & FLAG_BIAS) ? bias[block_n + wn * 64 + j * 16 + cl] : 0.f;

#pragma unroll
    for (int i = 0; i < 4; ++i) {
#pragma unroll
        for (int r = 0; r < 4; ++r) {
            long long row = block_m + wm * 64 + i * 16 + rq + r;
            if (row >= M) continue;
#pragma unroll
            for (int j = 0; j < 4; ++j) {
                long long col = block_n + wn * 64 + j * 16 + cl;
                float v = acc[i][j][r] + bv[j];
                if (flags & FLAG_GELU) {
                    // tanh-form GELU via sigmoid; |diff| vs erf-GELU < bf16 ulp of h1
                    float z = 1.5957691216f * v * (1.0f + 0.044715f * v * v);
                    v = v / (1.0f + __expf(-z));
                }
                if (flags & FLAG_RESID) v += resid[row * (long long)ldr + col];
                if (flags & FLAG_OUTBF16) Cb[row * (long long)ldc + col] = __float2bfloat16(v);
                else Cf[row * (long long)ldc + col] = v;
            }
        }
    }
}

static inline void launch_mfma(hipStream_t stream,
    const bf16* A, const bf16* Bt, const float* bias, const float* resid,
    float* Cf, bf16* Cb, int M, int N, int K, int ldc, int ldr, int flags)
{
    dim3 grid(N / 128, (M + 127) / 128, 1);
    mfma_gemm_k<<<grid, dim3(256), 0, stream>>>(A, Bt, bias, resid, Cf, Cb,
        M, N, K, K, K, ldc, ldr, 0, 0, 0, flags);
}

extern "C" void kernel_launch(void* const* d_in, const int* in_sizes, int n_in,
                              void* d_out, int out_size, void* d_ws, size_t ws_size,
                              hipStream_t stream)
{
    const float* images   = (const float*)d_in[0];
    const float* patch_W  = (const float*)d_in[1];
    const float* patch_b  = (const float*)d_in[2];
    const float* pos_emb  = (const float*)d_in[3];
    const float* cls      = (const float*)d_in[4];
    const float* ln1_g    = (const float*)d_in[5];
    const float* ln1_b    = (const float*)d_in[6];
    const float* Wq       = (const float*)d_in[7];
    const float* bq       = (const float*)d_in[8];
    const float* Wk       = (const float*)d_in[9];
    const float* bk       = (const float*)d_in[10];
    const float* Wv       = (const float*)d_in[11];
    const float* bv       = (const float*)d_in[12];
    const float* Wo       = (const float*)d_in[13];
    const float* bo       = (const float*)d_in[14];
    const float* ln2_g    = (const float*)d_in[15];
    const float* ln2_b    = (const float*)d_in[16];
    const float* W1       = (const float*)d_in[17];
    const float* b1       = (const float*)d_in[18];
    const float* W2       = (const float*)d_in[19];
    const float* b2       = (const float*)d_in[20];
    const float* head_g   = (const float*)d_in[21];
    const float* head_bn  = (const float*)d_in[22];
    const float* head_W   = (const float*)d_in[23];
    const float* head_bias= (const float*)d_in[24];
    float* out = (float*)d_out;

    // ---- workspace carve-up ----
    char* p = (char*)d_ws;
    auto alloc = [&](long long nbytes) { char* r = p; p += (nbytes + 255) & ~255LL; return r; };
    const long long SZ = (long long)NTOK * DMODEL;

    float* x      = (float*)alloc(SZ * 4);                          // residual fp32
    bf16*  xn     = (bf16*) alloc(SZ * 2);                          // LN out bf16
    bf16*  qkvb   = (bf16*) alloc((long long)NTOK * 2304 * 2);      // qkv bf16 (union ptmp fp32)
    float* ptmp   = (float*)qkvb;                                   // [6272,768] fp32
    bf16*  Vt     = (bf16*) alloc((long long)384 * 64 * 224 * 2);   // V transposed, padded
    bf16*  h1     = (bf16*) alloc((long long)NTOK * FFDIM * 2);     // FFN mid
    float* w2tmp  = (float*)alloc(2 * SZ * 4);                      // split-K partials
    bf16*  Ob     = (bf16*) alloc(SZ * 2);                          // attn out (union patches)
    bf16*  patches= Ob;
    bf16*  wqkv_t = (bf16*) alloc((long long)2304 * 768 * 2);
    bf16*  wo_t   = (bf16*) alloc((long long)768 * 768 * 2);
    bf16*  w1_t   = (bf16*) alloc((long long)3072 * 768 * 2);
    bf16*  w2_t   = (bf16*) alloc((long long)768 * 3072 * 2);
    bf16*  pw_t   = (bf16*) alloc((long long)768 * 768 * 2);
    float* bqkv   = (float*)alloc(2304 * 4);
    float* xcls   = (float*)alloc((long long)BATCHSZ * DMODEL * 4);

    // ---- embed ----
    extract_patches_k<<<dim3(BATCHSZ * NPATCH), dim3(256), 0, stream>>>(images, patches);
    transpose_conv_k<<<dim3(24, 24), dim3(256), 0, stream>>>(patch_W, pw_t, 768, 768);
    launch_mfma(stream, patches, pw_t, patch_b, nullptr, ptmp, nullptr,
                BATCHSZ * NPATCH, DMODEL, 768, DMODEL, 0, FLAG_BIAS);
    embed_k<<<dim3((int)(SZ / 256)), dim3(256), 0, stream>>>(ptmp, pos_emb, cls, x);

    const long long WQKV_L = (long long)NHEAD * DMODEL * HDIM;
    for (int l = 0; l < NLAYER; ++l) {
        conv_layer_k<<<dim3(6913), dim3(256), 0, stream>>>(
            Wq + (long long)l * WQKV_L, Wk + (long long)l * WQKV_L, Wv + (long long)l * WQKV_L,
            Wo + (long long)l * DMODEL * DMODEL,
            W1 + (long long)l * DMODEL * FFDIM,
            W2 + (long long)l * FFDIM * DMODEL,
            bq + (long long)l * 768, bk + (long long)l * 768, bv + (long long)l * 768,
            wqkv_t, wo_t, w1_t, w2_t, bqkv);

        // ln1 -> bf16
        ln_bf_k<<<dim3(NTOK), dim3(256), 0, stream>>>(
            x, DMODEL, ln1_g + l * DMODEL, ln1_b + l * DMODEL, xn, DMODEL);

        // fused QKV -> bf16 [6304][2304]
        launch_mfma(stream, xn, wqkv_t, bqkv, nullptr, nullptr, qkvb,
                    NTOK, 2304, DMODEL, 2304, 0, FLAG_BIAS | FLAG_OUTBF16);

        // V transpose
        vt_k<<<dim3(7, 2, 384), dim3(256), 0, stream>>>(qkvb, Vt);

        // fused MFMA attention -> Ob
        attn_k<<<dim3(4, 384), dim3(256), 0, stream>>>(qkvb, Vt, Ob);

        // x += Ob @ Wo + bo
        launch_mfma(stream, Ob, wo_t, bo + (long long)l * DMODEL, x, x, nullptr,
                    NTOK, DMODEL, DMODEL, DMODEL, DMODEL, FLAG_BIAS | FLAG_RESID);

        // ln2 -> bf16
        ln_bf_k<<<dim3(NTOK), dim3(256), 0, stream>>>(
            x, DMODEL, ln2_g + l * DMODEL, ln2_b + l * DMODEL, xn, DMODEL);

        // h1 = gelu(xn @ W1 + b1)
        launch_mfma(stream, xn, w1_t, b1 + (long long)l * FFDIM, nullptr, nullptr, h1,
                    NTOK, FFDIM, DMODEL, FFDIM, 0, FLAG_BIAS | FLAG_GELU | FLAG_OUTBF16);

        // W2 GEMM split-K (z=2, K=1536 each) -> w2tmp, then x += t0+t1+b2
        {
            dim3 grid(DMODEL / 128, (NTOK + 127) / 128, 2);
            mfma_gemm_k<<<grid, dim3(256), 0, stream>>>(
                h1, w2_t, nullptr, nullptr, w2tmp, nullptr,
                NTOK, DMODEL, 1536, FFDIM, FFDIM, DMODEL, 0,
                1536, 1536, SZ, 0);
            resid2_k<<<dim3((int)(SZ / 4 / 256)), dim3(256), 0, stream>>>(
                w2tmp, w2tmp + SZ, b2 + (long long)l * DMODEL, x);
        }
    }

    // ---- head ----
    ln_k<<<dim3(BATCHSZ), dim3(256), 0, stream>>>(
        x, (long long)S_LEN * DMODEL, head_g, head_bn, xcls, DMODEL);
    head_k<<<dim3(16, BATCHSZ), dim3(256), 0, stream>>>(xcls, head_W, head_bias, out);
}

// Round 4
// 4204.190 us; speedup vs baseline: 1.2630x; 1.0542x over previous
//
#include <hip/hip_runtime.h>
#include <hip/hip_bf16.h>
#include <math.h>

// ---- problem constants ----
#define S_LEN   197
#define NPATCH  196
#define BATCHSZ 32
#define DMODEL  768
#define NHEAD   12
#define HDIM    64
#define FFDIM   3072
#define NLAYER  12
#define NCLS    1000
#define NTOK    (BATCHSZ * S_LEN)   // 6304

#define FLAG_BIAS    1
#define FLAG_RESID   2
#define FLAG_GELU    4
#define FLAG_OUTBF16 8

typedef __attribute__((ext_vector_type(8))) short short8;
typedef __attribute__((ext_vector_type(4))) float f32x4;
typedef __hip_bfloat16 bf16;

#define GLOBAL_AS __attribute__((address_space(1)))
#define LDS_AS    __attribute__((address_space(3)))

static __device__ __forceinline__ short bf16bits(float x) {
    bf16 b = __float2bfloat16(x);
    return *reinterpret_cast<short*>(&b);
}

// =====================================================================
// patch extraction -> bf16 patches [32*196, 768]
// =====================================================================
__global__ __launch_bounds__(256) void extract_patches_k(
    const float* __restrict__ images, bf16* __restrict__ patches)
{
    int r = blockIdx.x;              // b*196 + p
    int b = r / NPATCH, p = r - b * NPATCH;
    int i = p / 14, j = p - i * 14;
    int tid = threadIdx.x;
#pragma unroll
    for (int t = 0; t < 3; ++t) {
        int k = tid + t * 256;       // 0..767
        int pi = k / 48;
        int rem = k - pi * 48;
        int pj = rem / 3;
        int c  = rem - pj * 3;
        long long src = (((long long)(b * 224 + i * 16 + pi)) * 224 + (j * 16 + pj)) * 3 + c;
        patches[(long long)r * 768 + k] = __float2bfloat16(images[src]);
    }
}

// x[b,s,:] = s==0 ? cls : ptmp[b*196+s-1,:] + pos[s-1,:]
__global__ __launch_bounds__(256) void embed_k(
    const float* __restrict__ ptmp, const float* __restrict__ pos,
    const float* __restrict__ cls, float* __restrict__ x)
{
    long long idx = (long long)blockIdx.x * 256 + threadIdx.x;  // 32*197*768
    int d = idx % DMODEL;
    long long r = idx / DMODEL;
    int b = r / S_LEN, s = r - (long long)b * S_LEN;
    float v;
    if (s == 0) v = cls[d];
    else v = ptmp[((long long)b * NPATCH + s - 1) * DMODEL + d] + pos[(long long)(s - 1) * DMODEL + d];
    x[idx] = v;
}

// =====================================================================
// tiled transpose + convert (patch_W only)
// =====================================================================
__global__ __launch_bounds__(256) void transpose_conv_k(
    const float* __restrict__ src, bf16* __restrict__ dst, int R, int C)
{
    __shared__ float t[32][33];
    int tx = threadIdx.x & 31, ty = threadIdx.x >> 5;
    int c0 = blockIdx.x * 32, r0 = blockIdx.y * 32;
#pragma unroll
    for (int i = 0; i < 4; ++i) {
        int r = r0 + ty + i * 8;
        if (r < R && c0 + tx < C) t[ty + i * 8][tx] = src[(long long)r * C + c0 + tx];
    }
    __syncthreads();
#pragma unroll
    for (int i = 0; i < 4; ++i) {
        int c = c0 + ty + i * 8;
        if (c < C && r0 + tx < R) dst[(long long)c * R + r0 + tx] = __float2bfloat16(t[tx][ty + i * 8]);
    }
}

// =====================================================================
// per-layer weight conversion -> bf16 [N][K] + qkv bias pack
// =====================================================================
__global__ __launch_bounds__(256) void conv_layer_k(
    const float* __restrict__ Wq, const float* __restrict__ Wk, const float* __restrict__ Wv,
    const float* __restrict__ Wo, const float* __restrict__ W1, const float* __restrict__ W2,
    const float* __restrict__ bq, const float* __restrict__ bk, const float* __restrict__ bv,
    bf16* __restrict__ wqkv_t, bf16* __restrict__ wo_t,
    bf16* __restrict__ w1_t, bf16* __restrict__ w2_t, float* __restrict__ bqkv)
{
    int t = blockIdx.x;
    int tid = threadIdx.x;
    if (t == 6912) {
        for (int i = tid; i < 2304; i += 256) {
            int m = i / 768, r = i - m * 768;
            bqkv[i] = (m == 0 ? bq : m == 1 ? bk : bv)[r];
        }
        return;
    }
    const float* src; bf16* dst;
    int C; long long dld;
    int r0, c0;
    if (t < 1728) {
        int slab = t / 48, rem = t - slab * 48;
        int mat = slab / 12, h = slab - mat * 12;
        src = (mat == 0 ? Wq : mat == 1 ? Wk : Wv) + (long long)h * 768 * 64;
        dst = wqkv_t + ((long long)mat * 768 + h * 64) * 768;
        C = 64; dld = 768;
        r0 = (rem >> 1) * 32; c0 = (rem & 1) * 32;
    } else if (t < 2304) {
        int rem = t - 1728;
        src = Wo; dst = wo_t; C = 768; dld = 768;
        r0 = (rem / 24) * 32; c0 = (rem % 24) * 32;
    } else if (t < 4608) {
        int rem = t - 2304;
        src = W1; dst = w1_t; C = 3072; dld = 768;
        r0 = (rem / 96) * 32; c0 = (rem % 96) * 32;
    } else {
        int rem = t - 4608;
        src = W2; dst = w2_t; C = 768; dld = 3072;
        r0 = (rem / 24) * 32; c0 = (rem % 24) * 32;
    }
    __shared__ float tile[32][33];
    int tx = tid & 31, ty = tid >> 5;
#pragma unroll
    for (int i = 0; i < 4; ++i)
        tile[ty + i * 8][tx] = src[(long long)(r0 + ty + i * 8) * C + c0 + tx];
    __syncthreads();
#pragma unroll
    for (int i = 0; i < 4; ++i)
        dst[(long long)(c0 + ty + i * 8) * dld + r0 + tx] = __float2bfloat16(tile[tx][ty + i * 8]);
}

// =====================================================================
// V transpose: qkv bf16 -> Vt [384][64][224], zero pad s>=197
// =====================================================================
__global__ __launch_bounds__(256) void vt_k(
    const bf16* __restrict__ qkv, bf16* __restrict__ Vt)
{
    int z = blockIdx.z;
    int b = z / NHEAD, h = z - b * NHEAD;
    int s0 = blockIdx.x * 32, e0 = blockIdx.y * 32;
    __shared__ bf16 t[32][33];
    int tx = threadIdx.x & 31, ty = threadIdx.x >> 5;
#pragma unroll
    for (int i = 0; i < 4; ++i) {
        int s = s0 + ty + i * 8;
        bf16 v = __float2bfloat16(0.f);
        if (s < S_LEN) v = qkv[((long long)(b * S_LEN + s)) * 2304 + 1536 + h * 64 + e0 + tx];
        t[ty + i * 8][tx] = v;
    }
    __syncthreads();
#pragma unroll
    for (int i = 0; i < 4; ++i) {
        int e = e0 + ty + i * 8;
        Vt[((long long)z * 64 + e) * 224 + s0 + tx] = t[tx][ty + i * 8];
    }
}

// =====================================================================
// LayerNorm over last dim (768)
// =====================================================================
__global__ __launch_bounds__(256) void ln_k(
    const float* __restrict__ xin, long long instride,
    const float* __restrict__ g, const float* __restrict__ b,
    float* __restrict__ xout, long long outstride)
{
    int row = blockIdx.x;
    const float* xr = xin + (long long)row * instride;
    float* orow = xout + (long long)row * outstride;
    int tid = threadIdx.x;
    float v0 = xr[tid], v1 = xr[tid + 256], v2 = xr[tid + 512];
    __shared__ float s[256];
    s[tid] = v0 + v1 + v2;
    __syncthreads();
    for (int st = 128; st > 0; st >>= 1) { if (tid < st) s[tid] += s[tid + st]; __syncthreads(); }
    float mean = s[0] * (1.0f / DMODEL);
    __syncthreads();
    float d0 = v0 - mean, d1 = v1 - mean, d2 = v2 - mean;
    s[tid] = d0 * d0 + d1 * d1 + d2 * d2;
    __syncthreads();
    for (int st = 128; st > 0; st >>= 1) { if (tid < st) s[tid] += s[tid + st]; __syncthreads(); }
    float rs = rsqrtf(s[0] * (1.0f / DMODEL) + 1e-5f);
    orow[tid]       = d0 * rs * g[tid]       + b[tid];
    orow[tid + 256] = d1 * rs * g[tid + 256] + b[tid + 256];
    orow[tid + 512] = d2 * rs * g[tid + 512] + b[tid + 512];
}

__global__ __launch_bounds__(256) void ln_bf_k(
    const float* __restrict__ xin, long long instride,
    const float* __restrict__ g, const float* __restrict__ b,
    bf16* __restrict__ xout, long long outstride)
{
    int row = blockIdx.x;
    const float* xr = xin + (long long)row * instride;
    bf16* orow = xout + (long long)row * outstride;
    int tid = threadIdx.x;
    float v0 = xr[tid], v1 = xr[tid + 256], v2 = xr[tid + 512];
    __shared__ float s[256];
    s[tid] = v0 + v1 + v2;
    __syncthreads();
    for (int st = 128; st > 0; st >>= 1) { if (tid < st) s[tid] += s[tid + st]; __syncthreads(); }
    float mean = s[0] * (1.0f / DMODEL);
    __syncthreads();
    float d0 = v0 - mean, d1 = v1 - mean, d2 = v2 - mean;
    s[tid] = d0 * d0 + d1 * d1 + d2 * d2;
    __syncthreads();
    for (int st = 128; st > 0; st >>= 1) { if (tid < st) s[tid] += s[tid + st]; __syncthreads(); }
    float rs = rsqrtf(s[0] * (1.0f / DMODEL) + 1e-5f);
    orow[tid]       = __float2bfloat16(d0 * rs * g[tid]       + b[tid]);
    orow[tid + 256] = __float2bfloat16(d1 * rs * g[tid + 256] + b[tid + 256]);
    orow[tid + 512] = __float2bfloat16(d2 * rs * g[tid + 512] + b[tid + 512]);
}

// =====================================================================
// MFMA fused attention (unchanged — verified correct)
// =====================================================================
__global__ __launch_bounds__(256) void attn_k(
    const bf16* __restrict__ qkvb, const bf16* __restrict__ Vtb,
    bf16* __restrict__ Ob)
{
    __shared__ short KP[14336];
    __shared__ short Vs[14336];

    int tid = threadIdx.x;
    int lane = tid & 63, wid = tid >> 6;
    int rl = lane & 15, quad = lane >> 4;
    int qb = blockIdx.x;
    int z = blockIdx.y;
    int b = z / NHEAD, h = z - b * NHEAD;
    const short* qg = (const short*)qkvb;
    const short* vg = (const short*)Vtb;

#pragma unroll
    for (int c = 0; c < 7; ++c) {
        int f = wid * 7 + c;
        if (f < 26) {
            int jn = f >> 1, s = f & 1;
            int krow = jn * 16 + rl; if (krow > 196) krow = 196;
            const short* src = qg + ((long long)(b * S_LEN + krow) * 2304 + 768 + h * 64 + s * 32 + quad * 8);
            __builtin_amdgcn_global_load_lds((GLOBAL_AS const void*)src,
                                             (LDS_AS void*)&KP[f * 512], 16, 0, 0);
        }
        {
            int et = f / 7, s2 = f - et * 7;
            int e = et * 16 + rl;
            const short* src = vg + ((long long)(z * 64 + e) * 224 + s2 * 32 + quad * 8);
            __builtin_amdgcn_global_load_lds((GLOBAL_AS const void*)src,
                                             (LDS_AS void*)&Vs[f * 512], 16, 0, 0);
        }
    }
    int qrow = qb * 64 + wid * 16 + rl;
    int qrc = qrow > 196 ? 196 : qrow;
    long long qbase = (long long)(b * S_LEN + qrc) * 2304 + h * 64 + quad * 8;
    short8 q0 = *(const short8*)(qg + qbase);
    short8 q1 = *(const short8*)(qg + qbase + 32);
    __syncthreads();

    f32x4 accS[13];
#pragma unroll
    for (int jn = 0; jn < 13; ++jn) accS[jn] = (f32x4){0.f, 0.f, 0.f, 0.f};
#pragma unroll
    for (int jn = 0; jn < 13; ++jn) {
        short8 b0 = *(const short8*)&KP[(jn * 2 + 0) * 512 + lane * 8];
        short8 b1 = *(const short8*)&KP[(jn * 2 + 1) * 512 + lane * 8];
        accS[jn] = __builtin_amdgcn_mfma_f32_16x16x32_bf16(q0, b0, accS[jn], 0, 0, 0);
        accS[jn] = __builtin_amdgcn_mfma_f32_16x16x32_bf16(q1, b1, accS[jn], 0, 0, 0);
    }
    __syncthreads();

    float mx[4] = {-1e30f, -1e30f, -1e30f, -1e30f};
    float sm[4] = {0.f, 0.f, 0.f, 0.f};
#pragma unroll
    for (int r = 0; r < 4; ++r) {
#pragma unroll
        for (int jn = 0; jn < 13; ++jn) {
            int col = jn * 16 + rl;
            if (col < S_LEN) mx[r] = fmaxf(mx[r], accS[jn][r] * 0.125f);
        }
#pragma unroll
        for (int d = 1; d < 16; d <<= 1) mx[r] = fmaxf(mx[r], __shfl_xor(mx[r], d, 64));
    }
    float pv[13][4];
#pragma unroll
    for (int jn = 0; jn < 13; ++jn) {
        int col = jn * 16 + rl;
#pragma unroll
        for (int r = 0; r < 4; ++r) {
            float p = (col < S_LEN) ? __expf(accS[jn][r] * 0.125f - mx[r]) : 0.f;
            pv[jn][r] = p;
            sm[r] += p;
        }
    }
#pragma unroll
    for (int r = 0; r < 4; ++r) {
#pragma unroll
        for (int d = 1; d < 16; d <<= 1) sm[r] += __shfl_xor(sm[r], d, 64);
        sm[r] = 1.0f / sm[r];
    }

    int pbase = wid * 7 * 512;
#pragma unroll
    for (int jn = 0; jn < 13; ++jn) {
        int col = jn * 16 + rl;
        int s2 = col >> 5, kk = col & 31;
        int lidx = (kk >> 3) * 16, j = kk & 7;
#pragma unroll
        for (int r = 0; r < 4; ++r) {
            int m = quad * 4 + r;
            KP[pbase + s2 * 512 + (m + lidx) * 8 + j] = bf16bits(pv[jn][r] * sm[r]);
        }
    }
    {
        int col = 208 + rl;
        int kk = col & 31;
        int lidx = (kk >> 3) * 16, j = kk & 7;
#pragma unroll
        for (int r = 0; r < 4; ++r) {
            int m = quad * 4 + r;
            KP[pbase + 6 * 512 + (m + lidx) * 8 + j] = 0;
        }
    }

    short8 pa[7];
#pragma unroll
    for (int s2 = 0; s2 < 7; ++s2) pa[s2] = *(const short8*)&KP[pbase + s2 * 512 + lane * 8];
    f32x4 accO[4];
#pragma unroll
    for (int et = 0; et < 4; ++et) accO[et] = (f32x4){0.f, 0.f, 0.f, 0.f};
#pragma unroll
    for (int et = 0; et < 4; ++et)
#pragma unroll
        for (int s2 = 0; s2 < 7; ++s2) {
            short8 bb = *(const short8*)&Vs[(et * 7 + s2) * 512 + lane * 8];
            accO[et] = __builtin_amdgcn_mfma_f32_16x16x32_bf16(pa[s2], bb, accO[et], 0, 0, 0);
        }

#pragma unroll
    for (int et = 0; et < 4; ++et) {
        int e = et * 16 + rl;
#pragma unroll
        for (int r = 0; r < 4; ++r) {
            int q = qb * 64 + wid * 16 + quad * 4 + r;
            if (q < S_LEN)
                Ob[((long long)(b * S_LEN + q)) * DMODEL + h * 64 + e] = __float2bfloat16(accO[et][r]);
        }
    }
}

// =====================================================================
// head: out[b][n] = dot(xcls[b], head_W[:,n]) + bias[n]
// =====================================================================
__global__ __launch_bounds__(256) void head_k(
    const float* __restrict__ xcls, const float* __restrict__ W,
    const float* __restrict__ bias, float* __restrict__ out)
{
    int nt = blockIdx.x, b = blockIdx.y;
    int tid = threadIdx.x;
    int nl = tid & 63, kq = tid >> 6;
    int n = nt * 64 + nl;
    __shared__ float xs[DMODEL];
    for (int i = tid; i < DMODEL; i += 256) xs[i] = xcls[(long long)b * DMODEL + i];
    __syncthreads();
    float sum = 0.f;
    if (n < NCLS) {
        const float* Wp = W + (long long)kq * 192 * NCLS + n;
#pragma unroll 8
        for (int k = 0; k < 192; ++k)
            sum = fmaf(xs[kq * 192 + k], Wp[(long long)k * NCLS], sum);
    }
    __shared__ float red[256];
    red[tid] = sum;
    __syncthreads();
    if (kq == 0 && n < NCLS)
        out[(long long)b * NCLS + n] = red[nl] + red[nl + 64] + red[nl + 128] + red[nl + 192] + bias[n];
}

// x[i] += t0[i] + t1[i] + b2[col]   (float4 vectorized, 768 cols)
__global__ __launch_bounds__(256) void resid2_k(
    const float* __restrict__ t0, const float* __restrict__ t1,
    const float* __restrict__ b2, float* __restrict__ x)
{
    long long i = (long long)blockIdx.x * 256 + threadIdx.x;   // float4 index
    int col4 = i % (DMODEL / 4);
    const f32x4* t0v = (const f32x4*)t0;
    const f32x4* t1v = (const f32x4*)t1;
    const f32x4* b2v = (const f32x4*)b2;
    f32x4* xv = (f32x4*)x;
    f32x4 v = xv[i];
    f32x4 a = t0v[i], b = t1v[i], c = b2v[col4];
    v.x += a.x + b.x + c.x;
    v.y += a.y + b.y + c.y;
    v.z += a.z + b.z + c.z;
    v.w += a.w + b.w + c.w;
    xv[i] = v;
}

// =====================================================================
// bf16 MFMA GEMM, 128x128 tile, BK=32, 3-buffer 2-deep pipeline with
// counted vmcnt, group-m L2 schedule (G=8 m-tiles hot in L2, n streams)
// composed with bijective XCD chunking; j-inner coalesced stores,
// fast GELU.  A [M][lda], Bt [N][ldb] bf16; K%32==0, N%128==0.
// =====================================================================
__global__ __launch_bounds__(256) void mfma_gemm_k(
    const bf16* __restrict__ A, const bf16* __restrict__ Bt,
    const float* __restrict__ bias, const float* __restrict__ resid,
    float* __restrict__ Cf, bf16* __restrict__ Cb,
    int M, int N, int K, int lda, int ldb, int ldc, int ldr,
    long long zA, long long zB, long long zC, int flags)
{
    __shared__ short As[3 * 4096];   // 3 buffers x 8 blocks x 512 shorts = 24KB
    __shared__ short Bs[3 * 4096];   // 24KB

    int tid = threadIdx.x;
    int lane = tid & 63, wid = tid >> 6;
    int wm = wid & 1, wn = wid >> 1;

    // ---- bijective XCD de-chunk (m204): contiguous rank range per XCD ----
    int gx = gridDim.x, gy = gridDim.y;
    int planes = gx * gy;
    int nwg = planes * gridDim.z;
    int lin = blockIdx.x + gx * (blockIdx.y + gy * blockIdx.z);
    int q8 = nwg >> 3, r8 = nwg & 7;
    int xcd = lin & 7, idx = lin >> 3;
    int rank = (xcd < r8) ? (xcd * (q8 + 1) + idx)
                          : (r8 * (q8 + 1) + (xcd - r8) * q8 + idx);
    int bz = rank / planes;
    int pr = rank - bz * planes;

    // ---- group-m ordering within plane: G m-tiles stay hot in L2,
    //      B-panels stream once per group (triton-style swizzle) ----
    const int GRP = 8;
    int tpg = GRP * gx;
    int grp = pr / tpg;
    int first_m = grp * GRP;
    int gsz = gy - first_m; if (gsz > GRP) gsz = GRP;
    int r2 = pr - grp * tpg;
    int by = first_m + r2 % gsz;     // m varies fastest within the group
    int bx = r2 / gsz;               // n streams across the group

    long long block_m = (long long)by * 128;
    long long block_n = (long long)bx * 128;

    const short* Ag = (const short*)A + (long long)bz * zA;
    const short* Bg = (const short*)Bt + (long long)bz * zB;
    if (Cf) Cf += (long long)bz * zC;
    if (Cb) Cb += (long long)bz * zC;

    int rl   = lane & 15;
    int quad = lane >> 4;

    // per-thread staging roles: waves 0-1 stage A (blocks 0..7), waves 2-3 B.
    const short* srcp[4];
    short* dstb[4];
#pragma unroll
    for (int c = 0; c < 4; ++c) {
        int bi = wid * 4 + c;
        int f = bi & 7;
        if (bi < 8) {
            long long grow = block_m + f * 16 + rl;
            if (grow >= M) grow = M - 1;
            srcp[c] = Ag + grow * lda + quad * 8;
            dstb[c] = &As[f * 512];
        } else {
            long long grow = block_n + f * 16 + rl;
            srcp[c] = Bg + grow * ldb + quad * 8;
            dstb[c] = &Bs[f * 512];
        }
    }

#define STAGE(BUF) do {                                                        \
    _Pragma("unroll")                                                          \
    for (int c = 0; c < 4; ++c) {                                              \
        __builtin_amdgcn_global_load_lds((GLOBAL_AS const void*)srcp[c],       \
            (LDS_AS void*)(dstb[c] + (BUF) * 4096), 16, 0, 0);                 \
        srcp[c] += 32;                                                         \
    } } while (0)

    f32x4 acc[4][4] = {};

    int nt = K >> 5;                 // K/32 tiles (>= 24 for all call sites)
    // prologue: tiles 0,1 into buffers 0,1
    STAGE(0);
    STAGE(1);
    int sbuf = 2, cbuf = 0;

    for (int t = 0; t < nt; ++t) {
        if (t + 2 < nt) {
            STAGE(sbuf);
            sbuf = (sbuf == 2) ? 0 : sbuf + 1;
            asm volatile("s_waitcnt vmcnt(8)" ::: "memory");   // tile t landed
        } else if (t + 1 < nt) {
            asm volatile("s_waitcnt vmcnt(4)" ::: "memory");
        } else {
            asm volatile("s_waitcnt vmcnt(0)" ::: "memory");
        }
        __builtin_amdgcn_s_barrier();   // all waves' tile-t DMA complete

        const short8* ap = (const short8*)(As + cbuf * 4096);
        const short8* bp = (const short8*)(Bs + cbuf * 4096);
        short8 a[4], b[4];
#pragma unroll
        for (int i = 0; i < 4; ++i) a[i] = ap[(wm * 4 + i) * 64 + lane];
#pragma unroll
        for (int j = 0; j < 4; ++j) b[j] = bp[(wn * 4 + j) * 64 + lane];
#pragma unroll
        for (int i = 0; i < 4; ++i)
#pragma unroll
            for (int j = 0; j < 4; ++j)
                acc[i][j] = __builtin_amdgcn_mfma_f32_16x16x32_bf16(a[i], b[j], acc[i][j], 0, 0, 0);

        __builtin_amdgcn_s_barrier();   // everyone done reading cbuf
        cbuf = (cbuf == 2) ? 0 : cbuf + 1;
    }
#undef STAGE

    // ---- epilogue: j-inner so each (i,r) emits 4 consecutive 32B chunks ----
    int cl = lane & 15;
    int rq = (lane >> 4) * 4;
    float bv[4];
#pragma unroll
    for (int j = 0; j < 4; ++j)
        bv[j] = (flags & FLAG_BIAS) ? bias[block_n + wn * 64 + j * 16 + cl] : 0.f;

#pragma unroll
    for (int i = 0; i < 4; ++i) {
#pragma unroll
        for (int r = 0; r < 4; ++r) {
            long long row = block_m + wm * 64 + i * 16 + rq + r;
            if (row >= M) continue;
#pragma unroll
            for (int j = 0; j < 4; ++j) {
                long long col = block_n + wn * 64 + j * 16 + cl;
                float v = acc[i][j][r] + bv[j];
                if (flags & FLAG_GELU) {
                    // tanh-form GELU via sigmoid; |diff| vs erf-GELU < bf16 ulp of h1
                    float z = 1.5957691216f * v * (1.0f + 0.044715f * v * v);
                    v = v / (1.0f + __expf(-z));
                }
                if (flags & FLAG_RESID) v += resid[row * (long long)ldr + col];
                if (flags & FLAG_OUTBF16) Cb[row * (long long)ldc + col] = __float2bfloat16(v);
                else Cf[row * (long long)ldc + col] = v;
            }
        }
    }
}

static inline void launch_mfma(hipStream_t stream,
    const bf16* A, const bf16* Bt, const float* bias, const float* resid,
    float* Cf, bf16* Cb, int M, int N, int K, int ldc, int ldr, int flags)
{
    dim3 grid(N / 128, (M + 127) / 128, 1);
    mfma_gemm_k<<<grid, dim3(256), 0, stream>>>(A, Bt, bias, resid, Cf, Cb,
        M, N, K, K, K, ldc, ldr, 0, 0, 0, flags);
}

extern "C" void kernel_launch(void* const* d_in, const int* in_sizes, int n_in,
                              void* d_out, int out_size, void* d_ws, size_t ws_size,
                              hipStream_t stream)
{
    const float* images   = (const float*)d_in[0];
    const float* patch_W  = (const float*)d_in[1];
    const float* patch_b  = (const float*)d_in[2];
    const float* pos_emb  = (const float*)d_in[3];
    const float* cls      = (const float*)d_in[4];
    const float* ln1_g    = (const float*)d_in[5];
    const float* ln1_b    = (const float*)d_in[6];
    const float* Wq       = (const float*)d_in[7];
    const float* bq       = (const float*)d_in[8];
    const float* Wk       = (const float*)d_in[9];
    const float* bk       = (const float*)d_in[10];
    const float* Wv       = (const float*)d_in[11];
    const float* bv       = (const float*)d_in[12];
    const float* Wo       = (const float*)d_in[13];
    const float* bo       = (const float*)d_in[14];
    const float* ln2_g    = (const float*)d_in[15];
    const float* ln2_b    = (const float*)d_in[16];
    const float* W1       = (const float*)d_in[17];
    const float* b1       = (const float*)d_in[18];
    const float* W2       = (const float*)d_in[19];
    const float* b2       = (const float*)d_in[20];
    const float* head_g   = (const float*)d_in[21];
    const float* head_bn  = (const float*)d_in[22];
    const float* head_W   = (const float*)d_in[23];
    const float* head_bias= (const float*)d_in[24];
    float* out = (float*)d_out;

    // ---- workspace carve-up ----
    char* p = (char*)d_ws;
    auto alloc = [&](long long nbytes) { char* r = p; p += (nbytes + 255) & ~255LL; return r; };
    const long long SZ = (long long)NTOK * DMODEL;

    float* x      = (float*)alloc(SZ * 4);                          // residual fp32
    bf16*  xn     = (bf16*) alloc(SZ * 2);                          // LN out bf16
    bf16*  qkvb   = (bf16*) alloc((long long)NTOK * 2304 * 2);      // qkv bf16 (union ptmp fp32)
    float* ptmp   = (float*)qkvb;                                   // [6272,768] fp32
    bf16*  Vt     = (bf16*) alloc((long long)384 * 64 * 224 * 2);   // V transposed, padded
    bf16*  h1     = (bf16*) alloc((long long)NTOK * FFDIM * 2);     // FFN mid
    float* w2tmp  = (float*)alloc(2 * SZ * 4);                      // split-K partials
    bf16*  Ob     = (bf16*) alloc(SZ * 2);                          // attn out (union patches)
    bf16*  patches= Ob;
    bf16*  wqkv_t = (bf16*) alloc((long long)2304 * 768 * 2);
    bf16*  wo_t   = (bf16*) alloc((long long)768 * 768 * 2);
    bf16*  w1_t   = (bf16*) alloc((long long)3072 * 768 * 2);
    bf16*  w2_t   = (bf16*) alloc((long long)768 * 3072 * 2);
    bf16*  pw_t   = (bf16*) alloc((long long)768 * 768 * 2);
    float* bqkv   = (float*)alloc(2304 * 4);
    float* xcls   = (float*)alloc((long long)BATCHSZ * DMODEL * 4);

    // ---- embed ----
    extract_patches_k<<<dim3(BATCHSZ * NPATCH), dim3(256), 0, stream>>>(images, patches);
    transpose_conv_k<<<dim3(24, 24), dim3(256), 0, stream>>>(patch_W, pw_t, 768, 768);
    launch_mfma(stream, patches, pw_t, patch_b, nullptr, ptmp, nullptr,
                BATCHSZ * NPATCH, DMODEL, 768, DMODEL, 0, FLAG_BIAS);
    embed_k<<<dim3((int)(SZ / 256)), dim3(256), 0, stream>>>(ptmp, pos_emb, cls, x);

    const long long WQKV_L = (long long)NHEAD * DMODEL * HDIM;
    for (int l = 0; l < NLAYER; ++l) {
        conv_layer_k<<<dim3(6913), dim3(256), 0, stream>>>(
            Wq + (long long)l * WQKV_L, Wk + (long long)l * WQKV_L, Wv + (long long)l * WQKV_L,
            Wo + (long long)l * DMODEL * DMODEL,
            W1 + (long long)l * DMODEL * FFDIM,
            W2 + (long long)l * FFDIM * DMODEL,
            bq + (long long)l * 768, bk + (long long)l * 768, bv + (long long)l * 768,
            wqkv_t, wo_t, w1_t, w2_t, bqkv);

        // ln1 -> bf16
        ln_bf_k<<<dim3(NTOK), dim3(256), 0, stream>>>(
            x, DMODEL, ln1_g + l * DMODEL, ln1_b + l * DMODEL, xn, DMODEL);

        // fused QKV -> bf16 [6304][2304]
        launch_mfma(stream, xn, wqkv_t, bqkv, nullptr, nullptr, qkvb,
                    NTOK, 2304, DMODEL, 2304, 0, FLAG_BIAS | FLAG_OUTBF16);

        // V transpose
        vt_k<<<dim3(7, 2, 384), dim3(256), 0, stream>>>(qkvb, Vt);

        // fused MFMA attention -> Ob
        attn_k<<<dim3(4, 384), dim3(256), 0, stream>>>(qkvb, Vt, Ob);

        // x += Ob @ Wo + bo
        launch_mfma(stream, Ob, wo_t, bo + (long long)l * DMODEL, x, x, nullptr,
                    NTOK, DMODEL, DMODEL, DMODEL, DMODEL, FLAG_BIAS | FLAG_RESID);

        // ln2 -> bf16
        ln_bf_k<<<dim3(NTOK), dim3(256), 0, stream>>>(
            x, DMODEL, ln2_g + l * DMODEL, ln2_b + l * DMODEL, xn, DMODEL);

        // h1 = gelu(xn @ W1 + b1)
        launch_mfma(stream, xn, w1_t, b1 + (long long)l * FFDIM, nullptr, nullptr, h1,
                    NTOK, FFDIM, DMODEL, FFDIM, 0, FLAG_BIAS | FLAG_GELU | FLAG_OUTBF16);

        // W2 GEMM split-K (z=2, K=1536 each) -> w2tmp, then x += t0+t1+b2
        {
            dim3 grid(DMODEL / 128, (NTOK + 127) / 128, 2);
            mfma_gemm_k<<<grid, dim3(256), 0, stream>>>(
                h1, w2_t, nullptr, nullptr, w2tmp, nullptr,
                NTOK, DMODEL, 1536, FFDIM, FFDIM, DMODEL, 0,
                1536, 1536, SZ, 0);
            resid2_k<<<dim3((int)(SZ / 4 / 256)), dim3(256), 0, stream>>>(
                w2tmp, w2tmp + SZ, b2 + (long long)l * DMODEL, x);
        }
    }

    // ---- head ----
    ln_k<<<dim3(BATCHSZ), dim3(256), 0, stream>>>(
        x, (long long)S_LEN * DMODEL, head_g, head_bn, xcls, DMODEL);
    head_k<<<dim3(16, BATCHSZ), dim3(256), 0, stream>>>(xcls, head_W, head_bias, out);
}

// Round 6
// 4041.904 us; speedup vs baseline: 1.3137x; 1.0402x over previous
//
#include <hip/hip_runtime.h>
#include <hip/hip_bf16.h>
#include <math.h>

// ---- problem constants ----
#define S_LEN   197
#define NPATCH  196
#define BATCHSZ 32
#define DMODEL  768
#define NHEAD   12
#define HDIM    64
#define FFDIM   3072
#define NLAYER  12
#define NCLS    1000
#define NTOK    (BATCHSZ * S_LEN)   // 6304

#define FLAG_BIAS    1
#define FLAG_RESID   2
#define FLAG_GELU    4
#define FLAG_OUTBF16 8

typedef __attribute__((ext_vector_type(8))) short short8;
typedef __attribute__((ext_vector_type(4))) float f32x4;
typedef __hip_bfloat16 bf16;

#define GLOBAL_AS __attribute__((address_space(1)))
#define LDS_AS    __attribute__((address_space(3)))

static __device__ __forceinline__ short bf16bits(float x) {
    bf16 b = __float2bfloat16(x);
    return *reinterpret_cast<short*>(&b);
}

// =====================================================================
// patch extraction -> bf16 patches [32*196, 768]
// =====================================================================
__global__ __launch_bounds__(256) void extract_patches_k(
    const float* __restrict__ images, bf16* __restrict__ patches)
{
    int r = blockIdx.x;              // b*196 + p
    int b = r / NPATCH, p = r - b * NPATCH;
    int i = p / 14, j = p - i * 14;
    int tid = threadIdx.x;
#pragma unroll
    for (int t = 0; t < 3; ++t) {
        int k = tid + t * 256;       // 0..767
        int pi = k / 48;
        int rem = k - pi * 48;
        int pj = rem / 3;
        int c  = rem - pj * 3;
        long long src = (((long long)(b * 224 + i * 16 + pi)) * 224 + (j * 16 + pj)) * 3 + c;
        patches[(long long)r * 768 + k] = __float2bfloat16(images[src]);
    }
}

// x[b,s,:] = s==0 ? cls : ptmp[b*196+s-1,:] + pos[s-1,:]
__global__ __launch_bounds__(256) void embed_k(
    const float* __restrict__ ptmp, const float* __restrict__ pos,
    const float* __restrict__ cls, float* __restrict__ x)
{
    long long idx = (long long)blockIdx.x * 256 + threadIdx.x;  // 32*197*768
    int d = idx % DMODEL;
    long long r = idx / DMODEL;
    int b = r / S_LEN, s = r - (long long)b * S_LEN;
    float v;
    if (s == 0) v = cls[d];
    else v = ptmp[((long long)b * NPATCH + s - 1) * DMODEL + d] + pos[(long long)(s - 1) * DMODEL + d];
    x[idx] = v;
}

// =====================================================================
// tiled transpose + convert (patch_W only)
// =====================================================================
__global__ __launch_bounds__(256) void transpose_conv_k(
    const float* __restrict__ src, bf16* __restrict__ dst, int R, int C)
{
    __shared__ float t[32][33];
    int tx = threadIdx.x & 31, ty = threadIdx.x >> 5;
    int c0 = blockIdx.x * 32, r0 = blockIdx.y * 32;
#pragma unroll
    for (int i = 0; i < 4; ++i) {
        int r = r0 + ty + i * 8;
        if (r < R && c0 + tx < C) t[ty + i * 8][tx] = src[(long long)r * C + c0 + tx];
    }
    __syncthreads();
#pragma unroll
    for (int i = 0; i < 4; ++i) {
        int c = c0 + ty + i * 8;
        if (c < C && r0 + tx < R) dst[(long long)c * R + r0 + tx] = __float2bfloat16(t[tx][ty + i * 8]);
    }
}

// =====================================================================
// per-layer weight conversion -> bf16 [N][K] + qkv bias pack
// =====================================================================
__global__ __launch_bounds__(256) void conv_layer_k(
    const float* __restrict__ Wq, const float* __restrict__ Wk, const float* __restrict__ Wv,
    const float* __restrict__ Wo, const float* __restrict__ W1, const float* __restrict__ W2,
    const float* __restrict__ bq, const float* __restrict__ bk, const float* __restrict__ bv,
    bf16* __restrict__ wqkv_t, bf16* __restrict__ wo_t,
    bf16* __restrict__ w1_t, bf16* __restrict__ w2_t, float* __restrict__ bqkv)
{
    int t = blockIdx.x;
    int tid = threadIdx.x;
    if (t == 6912) {
        for (int i = tid; i < 2304; i += 256) {
            int m = i / 768, r = i - m * 768;
            bqkv[i] = (m == 0 ? bq : m == 1 ? bk : bv)[r];
        }
        return;
    }
    const float* src; bf16* dst;
    int C; long long dld;
    int r0, c0;
    if (t < 1728) {
        int slab = t / 48, rem = t - slab * 48;
        int mat = slab / 12, h = slab - mat * 12;
        src = (mat == 0 ? Wq : mat == 1 ? Wk : Wv) + (long long)h * 768 * 64;
        dst = wqkv_t + ((long long)mat * 768 + h * 64) * 768;
        C = 64; dld = 768;
        r0 = (rem >> 1) * 32; c0 = (rem & 1) * 32;
    } else if (t < 2304) {
        int rem = t - 1728;
        src = Wo; dst = wo_t; C = 768; dld = 768;
        r0 = (rem / 24) * 32; c0 = (rem % 24) * 32;
    } else if (t < 4608) {
        int rem = t - 2304;
        src = W1; dst = w1_t; C = 3072; dld = 768;
        r0 = (rem / 96) * 32; c0 = (rem % 96) * 32;
    } else {
        int rem = t - 4608;
        src = W2; dst = w2_t; C = 768; dld = 3072;
        r0 = (rem / 24) * 32; c0 = (rem % 24) * 32;
    }
    __shared__ float tile[32][33];
    int tx = tid & 31, ty = tid >> 5;
#pragma unroll
    for (int i = 0; i < 4; ++i)
        tile[ty + i * 8][tx] = src[(long long)(r0 + ty + i * 8) * C + c0 + tx];
    __syncthreads();
#pragma unroll
    for (int i = 0; i < 4; ++i)
        dst[(long long)(c0 + ty + i * 8) * dld + r0 + tx] = __float2bfloat16(tile[tx][ty + i * 8]);
}

// =====================================================================
// V transpose: qkv bf16 -> Vt [384][64][224], zero pad s>=197
// =====================================================================
__global__ __launch_bounds__(256) void vt_k(
    const bf16* __restrict__ qkv, bf16* __restrict__ Vt)
{
    int z = blockIdx.z;
    int b = z / NHEAD, h = z - b * NHEAD;
    int s0 = blockIdx.x * 32, e0 = blockIdx.y * 32;
    __shared__ bf16 t[32][33];
    int tx = threadIdx.x & 31, ty = threadIdx.x >> 5;
#pragma unroll
    for (int i = 0; i < 4; ++i) {
        int s = s0 + ty + i * 8;
        bf16 v = __float2bfloat16(0.f);
        if (s < S_LEN) v = qkv[((long long)(b * S_LEN + s)) * 2304 + 1536 + h * 64 + e0 + tx];
        t[ty + i * 8][tx] = v;
    }
    __syncthreads();
#pragma unroll
    for (int i = 0; i < 4; ++i) {
        int e = e0 + ty + i * 8;
        Vt[((long long)z * 64 + e) * 224 + s0 + tx] = t[tx][ty + i * 8];
    }
}

// =====================================================================
// LayerNorm over last dim (768)
// =====================================================================
__global__ __launch_bounds__(256) void ln_k(
    const float* __restrict__ xin, long long instride,
    const float* __restrict__ g, const float* __restrict__ b,
    float* __restrict__ xout, long long outstride)
{
    int row = blockIdx.x;
    const float* xr = xin + (long long)row * instride;
    float* orow = xout + (long long)row * outstride;
    int tid = threadIdx.x;
    float v0 = xr[tid], v1 = xr[tid + 256], v2 = xr[tid + 512];
    __shared__ float s[256];
    s[tid] = v0 + v1 + v2;
    __syncthreads();
    for (int st = 128; st > 0; st >>= 1) { if (tid < st) s[tid] += s[tid + st]; __syncthreads(); }
    float mean = s[0] * (1.0f / DMODEL);
    __syncthreads();
    float d0 = v0 - mean, d1 = v1 - mean, d2 = v2 - mean;
    s[tid] = d0 * d0 + d1 * d1 + d2 * d2;
    __syncthreads();
    for (int st = 128; st > 0; st >>= 1) { if (tid < st) s[tid] += s[tid + st]; __syncthreads(); }
    float rs = rsqrtf(s[0] * (1.0f / DMODEL) + 1e-5f);
    orow[tid]       = d0 * rs * g[tid]       + b[tid];
    orow[tid + 256] = d1 * rs * g[tid + 256] + b[tid + 256];
    orow[tid + 512] = d2 * rs * g[tid + 512] + b[tid + 512];
}

__global__ __launch_bounds__(256) void ln_bf_k(
    const float* __restrict__ xin, long long instride,
    const float* __restrict__ g, const float* __restrict__ b,
    bf16* __restrict__ xout, long long outstride)
{
    int row = blockIdx.x;
    const float* xr = xin + (long long)row * instride;
    bf16* orow = xout + (long long)row * outstride;
    int tid = threadIdx.x;
    float v0 = xr[tid], v1 = xr[tid + 256], v2 = xr[tid + 512];
    __shared__ float s[256];
    s[tid] = v0 + v1 + v2;
    __syncthreads();
    for (int st = 128; st > 0; st >>= 1) { if (tid < st) s[tid] += s[tid + st]; __syncthreads(); }
    float mean = s[0] * (1.0f / DMODEL);
    __syncthreads();
    float d0 = v0 - mean, d1 = v1 - mean, d2 = v2 - mean;
    s[tid] = d0 * d0 + d1 * d1 + d2 * d2;
    __syncthreads();
    for (int st = 128; st > 0; st >>= 1) { if (tid < st) s[tid] += s[tid + st]; __syncthreads(); }
    float rs = rsqrtf(s[0] * (1.0f / DMODEL) + 1e-5f);
    orow[tid]       = __float2bfloat16(d0 * rs * g[tid]       + b[tid]);
    orow[tid + 256] = __float2bfloat16(d1 * rs * g[tid + 256] + b[tid + 256]);
    orow[tid + 512] = __float2bfloat16(d2 * rs * g[tid + 512] + b[tid + 512]);
}

// =====================================================================
// MFMA fused attention (unchanged — verified correct)
// =====================================================================
__global__ __launch_bounds__(256) void attn_k(
    const bf16* __restrict__ qkvb, const bf16* __restrict__ Vtb,
    bf16* __restrict__ Ob)
{
    __shared__ short KP[14336];
    __shared__ short Vs[14336];

    int tid = threadIdx.x;
    int lane = tid & 63, wid = tid >> 6;
    int rl = lane & 15, quad = lane >> 4;
    int qb = blockIdx.x;
    int z = blockIdx.y;
    int b = z / NHEAD, h = z - b * NHEAD;
    const short* qg = (const short*)qkvb;
    const short* vg = (const short*)Vtb;

#pragma unroll
    for (int c = 0; c < 7; ++c) {
        int f = wid * 7 + c;
        if (f < 26) {
            int jn = f >> 1, s = f & 1;
            int krow = jn * 16 + rl; if (krow > 196) krow = 196;
            const short* src = qg + ((long long)(b * S_LEN + krow) * 2304 + 768 + h * 64 + s * 32 + quad * 8);
            __builtin_amdgcn_global_load_lds((GLOBAL_AS const void*)src,
                                             (LDS_AS void*)&KP[f * 512], 16, 0, 0);
        }
        {
            int et = f / 7, s2 = f - et * 7;
            int e = et * 16 + rl;
            const short* src = vg + ((long long)(z * 64 + e) * 224 + s2 * 32 + quad * 8);
            __builtin_amdgcn_global_load_lds((GLOBAL_AS const void*)src,
                                             (LDS_AS void*)&Vs[f * 512], 16, 0, 0);
        }
    }
    int qrow = qb * 64 + wid * 16 + rl;
    int qrc = qrow > 196 ? 196 : qrow;
    long long qbase = (long long)(b * S_LEN + qrc) * 2304 + h * 64 + quad * 8;
    short8 q0 = *(const short8*)(qg + qbase);
    short8 q1 = *(const short8*)(qg + qbase + 32);
    __syncthreads();

    f32x4 accS[13];
#pragma unroll
    for (int jn = 0; jn < 13; ++jn) accS[jn] = (f32x4){0.f, 0.f, 0.f, 0.f};
#pragma unroll
    for (int jn = 0; jn < 13; ++jn) {
        short8 b0 = *(const short8*)&KP[(jn * 2 + 0) * 512 + lane * 8];
        short8 b1 = *(const short8*)&KP[(jn * 2 + 1) * 512 + lane * 8];
        accS[jn] = __builtin_amdgcn_mfma_f32_16x16x32_bf16(q0, b0, accS[jn], 0, 0, 0);
        accS[jn] = __builtin_amdgcn_mfma_f32_16x16x32_bf16(q1, b1, accS[jn], 0, 0, 0);
    }
    __syncthreads();

    float mx[4] = {-1e30f, -1e30f, -1e30f, -1e30f};
    float sm[4] = {0.f, 0.f, 0.f, 0.f};
#pragma unroll
    for (int r = 0; r < 4; ++r) {
#pragma unroll
        for (int jn = 0; jn < 13; ++jn) {
            int col = jn * 16 + rl;
            if (col < S_LEN) mx[r] = fmaxf(mx[r], accS[jn][r] * 0.125f);
        }
#pragma unroll
        for (int d = 1; d < 16; d <<= 1) mx[r] = fmaxf(mx[r], __shfl_xor(mx[r], d, 64));
    }
    float pv[13][4];
#pragma unroll
    for (int jn = 0; jn < 13; ++jn) {
        int col = jn * 16 + rl;
#pragma unroll
        for (int r = 0; r < 4; ++r) {
            float p = (col < S_LEN) ? __expf(accS[jn][r] * 0.125f - mx[r]) : 0.f;
            pv[jn][r] = p;
            sm[r] += p;
        }
    }
#pragma unroll
    for (int r = 0; r < 4; ++r) {
#pragma unroll
        for (int d = 1; d < 16; d <<= 1) sm[r] += __shfl_xor(sm[r], d, 64);
        sm[r] = 1.0f / sm[r];
    }

    int pbase = wid * 7 * 512;
#pragma unroll
    for (int jn = 0; jn < 13; ++jn) {
        int col = jn * 16 + rl;
        int s2 = col >> 5, kk = col & 31;
        int lidx = (kk >> 3) * 16, j = kk & 7;
#pragma unroll
        for (int r = 0; r < 4; ++r) {
            int m = quad * 4 + r;
            KP[pbase + s2 * 512 + (m + lidx) * 8 + j] = bf16bits(pv[jn][r] * sm[r]);
        }
    }
    {
        int col = 208 + rl;
        int kk = col & 31;
        int lidx = (kk >> 3) * 16, j = kk & 7;
#pragma unroll
        for (int r = 0; r < 4; ++r) {
            int m = quad * 4 + r;
            KP[pbase + 6 * 512 + (m + lidx) * 8 + j] = 0;
        }
    }

    short8 pa[7];
#pragma unroll
    for (int s2 = 0; s2 < 7; ++s2) pa[s2] = *(const short8*)&KP[pbase + s2 * 512 + lane * 8];
    f32x4 accO[4];
#pragma unroll
    for (int et = 0; et < 4; ++et) accO[et] = (f32x4){0.f, 0.f, 0.f, 0.f};
#pragma unroll
    for (int et = 0; et < 4; ++et)
#pragma unroll
        for (int s2 = 0; s2 < 7; ++s2) {
            short8 bb = *(const short8*)&Vs[(et * 7 + s2) * 512 + lane * 8];
            accO[et] = __builtin_amdgcn_mfma_f32_16x16x32_bf16(pa[s2], bb, accO[et], 0, 0, 0);
        }

#pragma unroll
    for (int et = 0; et < 4; ++et) {
        int e = et * 16 + rl;
#pragma unroll
        for (int r = 0; r < 4; ++r) {
            int q = qb * 64 + wid * 16 + quad * 4 + r;
            if (q < S_LEN)
                Ob[((long long)(b * S_LEN + q)) * DMODEL + h * 64 + e] = __float2bfloat16(accO[et][r]);
        }
    }
}

// =====================================================================
// head: out[b][n] = dot(xcls[b], head_W[:,n]) + bias[n]
// =====================================================================
__global__ __launch_bounds__(256) void head_k(
    const float* __restrict__ xcls, const float* __restrict__ W,
    const float* __restrict__ bias, float* __restrict__ out)
{
    int nt = blockIdx.x, b = blockIdx.y;
    int tid = threadIdx.x;
    int nl = tid & 63, kq = tid >> 6;
    int n = nt * 64 + nl;
    __shared__ float xs[DMODEL];
    for (int i = tid; i < DMODEL; i += 256) xs[i] = xcls[(long long)b * DMODEL + i];
    __syncthreads();
    float sum = 0.f;
    if (n < NCLS) {
        const float* Wp = W + (long long)kq * 192 * NCLS + n;
#pragma unroll 8
        for (int k = 0; k < 192; ++k)
            sum = fmaf(xs[kq * 192 + k], Wp[(long long)k * NCLS], sum);
    }
    __shared__ float red[256];
    red[tid] = sum;
    __syncthreads();
    if (kq == 0 && n < NCLS)
        out[(long long)b * NCLS + n] = red[nl] + red[nl + 64] + red[nl + 128] + red[nl + 192] + bias[n];
}

// x[i] += t0[i] + t1[i] + b2[col]   (float4 vectorized, 768 cols)
__global__ __launch_bounds__(256) void resid2_k(
    const float* __restrict__ t0, const float* __restrict__ t1,
    const float* __restrict__ b2, float* __restrict__ x)
{
    long long i = (long long)blockIdx.x * 256 + threadIdx.x;   // float4 index
    int col4 = i % (DMODEL / 4);
    const f32x4* t0v = (const f32x4*)t0;
    const f32x4* t1v = (const f32x4*)t1;
    const f32x4* b2v = (const f32x4*)b2;
    f32x4* xv = (f32x4*)x;
    f32x4 v = xv[i];
    f32x4 a = t0v[i], b = t1v[i], c = b2v[col4];
    v.x += a.x + b.x + c.x;
    v.y += a.y + b.y + c.y;
    v.z += a.z + b.z + c.z;
    v.w += a.w + b.w + c.w;
    xv[i] = v;
}

// =====================================================================
// bf16 MFMA GEMM, 256x128 tile, 8 waves (512 thr), BK=32, 3-buffer
// 2-deep pipeline with counted vmcnt, group-m L2 schedule + bijective
// XCD chunking, setprio around MFMA, j-inner coalesced stores, fast
// GELU.  A [M][lda], Bt [N][ldb] bf16; K%32==0, N%128==0.
// Per wave: 64x64 output (wm=wid&3 m-strip, wn=wid>>2 n-strip).
// LDS: As 16 frag x 512 x 3buf = 48KB, Bs 8 frag x 512 x 3buf = 24KB.
// =====================================================================
__global__ __launch_bounds__(512) void mfma_gemm_k(
    const bf16* __restrict__ A, const bf16* __restrict__ Bt,
    const float* __restrict__ bias, const float* __restrict__ resid,
    float* __restrict__ Cf, bf16* __restrict__ Cb,
    int M, int N, int K, int lda, int ldb, int ldc, int ldr,
    long long zA, long long zB, long long zC, int flags)
{
    __shared__ short As[3 * 8192];   // 3 buf x 16 frag-blocks x 512 shorts
    __shared__ short Bs[3 * 4096];   // 3 buf x  8 frag-blocks x 512 shorts

    int tid = threadIdx.x;
    int lane = tid & 63, wid = tid >> 6;        // wid 0..7
    int wm = wid & 3, wn = wid >> 2;            // 4 m-strips x 2 n-strips

    // ---- bijective XCD de-chunk (m204): contiguous rank range per XCD ----
    int gx = gridDim.x, gy = gridDim.y;
    int planes = gx * gy;
    int nwg = planes * gridDim.z;
    int lin = blockIdx.x + gx * (blockIdx.y + gy * blockIdx.z);
    int q8 = nwg >> 3, r8 = nwg & 7;
    int xcd = lin & 7, idx = lin >> 3;
    int rank = (xcd < r8) ? (xcd * (q8 + 1) + idx)
                          : (r8 * (q8 + 1) + (xcd - r8) * q8 + idx);
    int bz = rank / planes;
    int pr = rank - bz * planes;

    // ---- group-m ordering: G m-tiles hot in L2, B streams per group ----
    const int GRP = 8;
    int tpg = GRP * gx;
    int grp = pr / tpg;
    int first_m = grp * GRP;
    int gsz = gy - first_m; if (gsz > GRP) gsz = GRP;
    int r2 = pr - grp * tpg;
    int by = first_m + r2 % gsz;     // m varies fastest within the group
    int bx = r2 / gsz;               // n streams across the group

    long long block_m = (long long)by * 256;
    long long block_n = (long long)bx * 128;

    const short* Ag = (const short*)A + (long long)bz * zA;
    const short* Bg = (const short*)Bt + (long long)bz * zB;
    if (Cf) Cf += (long long)bz * zC;
    if (Cb) Cb += (long long)bz * zC;

    int rl   = lane & 15;
    int quad = lane >> 4;

    // staging: 24 frag-blocks (16 A + 8 B), 3 per wave, 1KB each.
    // block f<16: A rows f*16..+16; f>=16: B rows (f-16)*16..+16.
    const short* srcp[3];
    short* dstb[3];
    int dstr[3];
#pragma unroll
    for (int c = 0; c < 3; ++c) {
        int bi = wid * 3 + c;        // 0..23
        if (bi < 16) {
            long long grow = block_m + bi * 16 + rl;
            if (grow >= M) grow = M - 1;
            srcp[c] = Ag + grow * lda + quad * 8;
            dstb[c] = &As[bi * 512];
            dstr[c] = 8192;
        } else {
            int f = bi - 16;
            long long grow = block_n + f * 16 + rl;
            srcp[c] = Bg + grow * ldb + quad * 8;
            dstb[c] = &Bs[f * 512];
            dstr[c] = 4096;
        }
    }

#define STAGE(BUF) do {                                                        \
    _Pragma("unroll")                                                          \
    for (int c = 0; c < 3; ++c) {                                              \
        __builtin_amdgcn_global_load_lds((GLOBAL_AS const void*)srcp[c],       \
            (LDS_AS void*)(dstb[c] + (BUF) * dstr[c]), 16, 0, 0);              \
        srcp[c] += 32;                                                         \
    } } while (0)

    f32x4 acc[4][4] = {};

    int nt = K >> 5;                 // K/32 tiles (>= 24 for all call sites)
    STAGE(0);
    STAGE(1);
    int sbuf = 2, cbuf = 0;

    for (int t = 0; t < nt; ++t) {
        if (t + 2 < nt) {
            STAGE(sbuf);
            sbuf = (sbuf == 2) ? 0 : sbuf + 1;
            asm volatile("s_waitcnt vmcnt(6)" ::: "memory");   // tile t landed
        } else if (t + 1 < nt) {
            asm volatile("s_waitcnt vmcnt(3)" ::: "memory");
        } else {
            asm volatile("s_waitcnt vmcnt(0)" ::: "memory");
        }
        __builtin_amdgcn_s_barrier();   // all waves' tile-t DMA complete

        const short8* ap = (const short8*)(As + cbuf * 8192);
        const short8* bp = (const short8*)(Bs + cbuf * 4096);
        short8 a[4], b[4];
#pragma unroll
        for (int i = 0; i < 4; ++i) a[i] = ap[(wm * 4 + i) * 64 + lane];
#pragma unroll
        for (int j = 0; j < 4; ++j) b[j] = bp[(wn * 4 + j) * 64 + lane];
        __builtin_amdgcn_s_setprio(1);
#pragma unroll
        for (int i = 0; i < 4; ++i)
#pragma unroll
            for (int j = 0; j < 4; ++j)
                acc[i][j] = __builtin_amdgcn_mfma_f32_16x16x32_bf16(a[i], b[j], acc[i][j], 0, 0, 0);
        __builtin_amdgcn_s_setprio(0);

        __builtin_amdgcn_s_barrier();   // everyone done reading cbuf
        cbuf = (cbuf == 2) ? 0 : cbuf + 1;
    }
#undef STAGE

    // ---- epilogue: j-inner so each (i,r) emits 4 consecutive 32B chunks ----
    int cl = lane & 15;
    int rq = (lane >> 4) * 4;
    float bv[4];
#pragma unroll
    for (int j = 0; j < 4; ++j)
        bv[j] = (flags & FLAG_BIAS) ? bias[block_n + wn * 64 + j * 16 + cl] : 0.f;

#pragma unroll
    for (int i = 0; i < 4; ++i) {
#pragma unroll
        for (int r = 0; r < 4; ++r) {
            long long row = block_m + wm * 64 + i * 16 + rq + r;
            if (row >= M) continue;
#pragma unroll
            for (int j = 0; j < 4; ++j) {
                long long col = block_n + wn * 64 + j * 16 + cl;
                float v = acc[i][j][r] + bv[j];
                if (flags & FLAG_GELU) {
                    // tanh-form GELU via sigmoid; |diff| vs erf-GELU < bf16 ulp of h1
                    float z = 1.5957691216f * v * (1.0f + 0.044715f * v * v);
                    v = v / (1.0f + __expf(-z));
                }
                if (flags & FLAG_RESID) v += resid[row * (long long)ldr + col];
                if (flags & FLAG_OUTBF16) Cb[row * (long long)ldc + col] = __float2bfloat16(v);
                else Cf[row * (long long)ldc + col] = v;
            }
        }
    }
}

static inline void launch_mfma(hipStream_t stream,
    const bf16* A, const bf16* Bt, const float* bias, const float* resid,
    float* Cf, bf16* Cb, int M, int N, int K, int ldc, int ldr, int flags)
{
    dim3 grid(N / 128, (M + 255) / 256, 1);
    mfma_gemm_k<<<grid, dim3(512), 0, stream>>>(A, Bt, bias, resid, Cf, Cb,
        M, N, K, K, K, ldc, ldr, 0, 0, 0, flags);
}

extern "C" void kernel_launch(void* const* d_in, const int* in_sizes, int n_in,
                              void* d_out, int out_size, void* d_ws, size_t ws_size,
                              hipStream_t stream)
{
    const float* images   = (const float*)d_in[0];
    const float* patch_W  = (const float*)d_in[1];
    const float* patch_b  = (const float*)d_in[2];
    const float* pos_emb  = (const float*)d_in[3];
    const float* cls      = (const float*)d_in[4];
    const float* ln1_g    = (const float*)d_in[5];
    const float* ln1_b    = (const float*)d_in[6];
    const float* Wq       = (const float*)d_in[7];
    const float* bq       = (const float*)d_in[8];
    const float* Wk       = (const float*)d_in[9];
    const float* bk       = (const float*)d_in[10];
    const float* Wv       = (const float*)d_in[11];
    const float* bv       = (const float*)d_in[12];
    const float* Wo       = (const float*)d_in[13];
    const float* bo       = (const float*)d_in[14];
    const float* ln2_g    = (const float*)d_in[15];
    const float* ln2_b    = (const float*)d_in[16];
    const float* W1       = (const float*)d_in[17];
    const float* b1       = (const float*)d_in[18];
    const float* W2       = (const float*)d_in[19];
    const float* b2       = (const float*)d_in[20];
    const float* head_g   = (const float*)d_in[21];
    const float* head_bn  = (const float*)d_in[22];
    const float* head_W   = (const float*)d_in[23];
    const float* head_bias= (const float*)d_in[24];
    float* out = (float*)d_out;

    // ---- workspace carve-up ----
    char* p = (char*)d_ws;
    auto alloc = [&](long long nbytes) { char* r = p; p += (nbytes + 255) & ~255LL; return r; };
    const long long SZ = (long long)NTOK * DMODEL;

    float* x      = (float*)alloc(SZ * 4);                          // residual fp32
    bf16*  xn     = (bf16*) alloc(SZ * 2);                          // LN out bf16
    bf16*  qkvb   = (bf16*) alloc((long long)NTOK * 2304 * 2);      // qkv bf16 (union ptmp fp32)
    float* ptmp   = (float*)qkvb;                                   // [6272,768] fp32
    bf16*  Vt     = (bf16*) alloc((long long)384 * 64 * 224 * 2);   // V transposed, padded
    bf16*  h1     = (bf16*) alloc((long long)NTOK * FFDIM * 2);     // FFN mid
    float* w2tmp  = (float*)alloc(2 * SZ * 4);                      // split-K partials
    bf16*  Ob     = (bf16*) alloc(SZ * 2);                          // attn out (union patches)
    bf16*  patches= Ob;
    bf16*  wqkv_t = (bf16*) alloc((long long)2304 * 768 * 2);
    bf16*  wo_t   = (bf16*) alloc((long long)768 * 768 * 2);
    bf16*  w1_t   = (bf16*) alloc((long long)3072 * 768 * 2);
    bf16*  w2_t   = (bf16*) alloc((long long)768 * 3072 * 2);
    bf16*  pw_t   = (bf16*) alloc((long long)768 * 768 * 2);
    float* bqkv   = (float*)alloc(2304 * 4);
    float* xcls   = (float*)alloc((long long)BATCHSZ * DMODEL * 4);

    // ---- embed ----
    extract_patches_k<<<dim3(BATCHSZ * NPATCH), dim3(256), 0, stream>>>(images, patches);
    transpose_conv_k<<<dim3(24, 24), dim3(256), 0, stream>>>(patch_W, pw_t, 768, 768);
    launch_mfma(stream, patches, pw_t, patch_b, nullptr, ptmp, nullptr,
                BATCHSZ * NPATCH, DMODEL, 768, DMODEL, 0, FLAG_BIAS);
    embed_k<<<dim3((int)(SZ / 256)), dim3(256), 0, stream>>>(ptmp, pos_emb, cls, x);

    const long long WQKV_L = (long long)NHEAD * DMODEL * HDIM;
    for (int l = 0; l < NLAYER; ++l) {
        conv_layer_k<<<dim3(6913), dim3(256), 0, stream>>>(
            Wq + (long long)l * WQKV_L, Wk + (long long)l * WQKV_L, Wv + (long long)l * WQKV_L,
            Wo + (long long)l * DMODEL * DMODEL,
            W1 + (long long)l * DMODEL * FFDIM,
            W2 + (long long)l * FFDIM * DMODEL,
            bq + (long long)l * 768, bk + (long long)l * 768, bv + (long long)l * 768,
            wqkv_t, wo_t, w1_t, w2_t, bqkv);

        // ln1 -> bf16
        ln_bf_k<<<dim3(NTOK), dim3(256), 0, stream>>>(
            x, DMODEL, ln1_g + l * DMODEL, ln1_b + l * DMODEL, xn, DMODEL);

        // fused QKV -> bf16 [6304][2304]
        launch_mfma(stream, xn, wqkv_t, bqkv, nullptr, nullptr, qkvb,
                    NTOK, 2304, DMODEL, 2304, 0, FLAG_BIAS | FLAG_OUTBF16);

        // V transpose
        vt_k<<<dim3(7, 2, 384), dim3(256), 0, stream>>>(qkvb, Vt);

        // fused MFMA attention -> Ob
        attn_k<<<dim3(4, 384), dim3(256), 0, stream>>>(qkvb, Vt, Ob);

        // x += Ob @ Wo + bo
        launch_mfma(stream, Ob, wo_t, bo + (long long)l * DMODEL, x, x, nullptr,
                    NTOK, DMODEL, DMODEL, DMODEL, DMODEL, FLAG_BIAS | FLAG_RESID);

        // ln2 -> bf16
        ln_bf_k<<<dim3(NTOK), dim3(256), 0, stream>>>(
            x, DMODEL, ln2_g + l * DMODEL, ln2_b + l * DMODEL, xn, DMODEL);

        // h1 = gelu(xn @ W1 + b1)
        launch_mfma(stream, xn, w1_t, b1 + (long long)l * FFDIM, nullptr, nullptr, h1,
                    NTOK, FFDIM, DMODEL, FFDIM, 0, FLAG_BIAS | FLAG_GELU | FLAG_OUTBF16);

        // W2 GEMM split-K (z=2, K=1536 each) -> w2tmp, then x += t0+t1+b2
        {
            dim3 grid(DMODEL / 128, (NTOK + 255) / 256, 2);
            mfma_gemm_k<<<grid, dim3(512), 0, stream>>>(
                h1, w2_t, nullptr, nullptr, w2tmp, nullptr,
                NTOK, DMODEL, 1536, FFDIM, FFDIM, DMODEL, 0,
                1536, 1536, SZ, 0);
            resid2_k<<<dim3((int)(SZ / 4 / 256)), dim3(256), 0, stream>>>(
                w2tmp, w2tmp + SZ, b2 + (long long)l * DMODEL, x);
        }
    }

    // ---- head ----
    ln_k<<<dim3(BATCHSZ), dim3(256), 0, stream>>>(
        x, (long long)S_LEN * DMODEL, head_g, head_bn, xcls, DMODEL);
    head_k<<<dim3(16, BATCHSZ), dim3(256), 0, stream>>>(xcls, head_W, head_bias, out);
}